// Round 11
// baseline (612.680 us; speedup 1.0000x reference)
//
#include <hip/hip_runtime.h>

typedef unsigned int uint32;
typedef unsigned short u16;
typedef float fx4 __attribute__((ext_vector_type(4)));
typedef uint32 u32x4 __attribute__((ext_vector_type(4)));

typedef const __attribute__((address_space(1))) void gvoid;
typedef __attribute__((address_space(3))) void lvoid;

#define MFMA_BF16_16x16x32(acc, a, b) \
  asm("v_mfma_f32_16x16x32_bf16 %0, %1, %2, %0" : "+v"(acc) : "v"(a), "v"(b))

#define WAIT_LGKM0() asm volatile("s_waitcnt lgkmcnt(0)" ::: "memory")
#define WAIT_LGKM2() asm volatile("s_waitcnt lgkmcnt(2)" ::: "memory")
#define WAIT_VM0()   asm volatile("s_waitcnt vmcnt(0)" ::: "memory")
#define WAIT_VM3()   asm volatile("s_waitcnt vmcnt(3)" ::: "memory")
#define WAIT_VM6()   asm volatile("s_waitcnt vmcnt(6)" ::: "memory")
#define WAIT_VM8()   asm volatile("s_waitcnt vmcnt(8)" ::: "memory")
#define SFENCE()     __builtin_amdgcn_sched_barrier(0)
#define BARRIER()    do { __builtin_amdgcn_s_barrier(); asm volatile("" ::: "memory"); } while (0)

__device__ __forceinline__ u16 f2bf_rne(float f) {
  uint32 u = __builtin_bit_cast(uint32, f);
  u += 0x7FFFu + ((u >> 16) & 1u);
  return (u16)(u >> 16);
}

__device__ __forceinline__ uint32 cvt_pk_bf16(float lo, float hi) {
  uint32 r;
  asm("v_cvt_pk_bf16_f32 %0, %1, %2" : "=v"(r) : "v"(lo), "v"(hi));
  return r;
}

// ---------------------------------------------------------------------------
// x (fp32) -> bf16
// ---------------------------------------------------------------------------
__global__ __launch_bounds__(256) void cvtx_kernel(const float* __restrict__ x,
                                                   u16* __restrict__ xb) {
  const int i = blockIdx.x * 256 + threadIdx.x;
  float4 v = ((const float4*)x)[i];
  ushort4 o;
  o.x = f2bf_rne(v.x);
  o.y = f2bf_rne(v.y);
  o.z = f2bf_rne(v.z);
  o.w = f2bf_rne(v.w);
  ((ushort4*)xb)[i] = o;
}

// ---------------------------------------------------------------------------
// decode body: dec[t,r,d] = scales[t]*0.25 * sum_k cw[idx[t,r,k], d] (bf16)
// ---------------------------------------------------------------------------
__device__ __forceinline__ void decode_body(
    int bid, const float* __restrict__ cw, const int* __restrict__ indices,
    const float* __restrict__ scales, u16* __restrict__ dec) {
  const int tid = threadIdx.x;
#pragma unroll 1
  for (int rr = 0; rr < 16; ++rr) {
    const int row = bid * 16 + rr;       // t*512 + r
    const int t = row >> 9;
    const int* ip = indices + (size_t)row * 4;
    const float* c0 = cw + (size_t)ip[0] * 4096;
    const float* c1 = cw + (size_t)ip[1] * 4096;
    const float* c2 = cw + (size_t)ip[2] * 4096;
    const float* c3 = cw + (size_t)ip[3] * 4096;
    const float s = scales[t] * 0.25f;
    u16* orow = dec + (size_t)row * 4096;
#pragma unroll
    for (int j = 0; j < 4; ++j) {
      const int d = j * 1024 + tid * 4;
      float4 a = *(const float4*)(c0 + d);
      float4 b = *(const float4*)(c1 + d);
      float4 c = *(const float4*)(c2 + d);
      float4 e = *(const float4*)(c3 + d);
      ushort4 o;
      o.x = f2bf_rne((a.x + b.x + c.x + e.x) * s);
      o.y = f2bf_rne((a.y + b.y + c.y + e.y) * s);
      o.z = f2bf_rne((a.z + b.z + c.z + e.z) * s);
      o.w = f2bf_rne((a.w + b.w + c.w + e.w) * s);
      *(ushort4*)(orow + d) = o;
    }
  }
}

// ---------------------------------------------------------------------------
// Fused: blocks [0,256) decode; blocks [256,1280) z[t] = x_bf16 @ rot[t]^T.
// GEMM: per-t M=512,N=4096,K=4096; 128x128 tile, BK=32, 4 waves (2x2).
// B IS NEVER STAGED IN LDS: each wave loads its 4 MFMA B-fragments straight
// from rot (16 rows x 128B contiguous per dwordx4 pair -- line-efficient)
// and converts fp32->bf16 in-register (v_cvt_pk_bf16_f32). This halves LDS
// traffic (the round-10 bottleneck: 96KB -> 24KB per block-step) and deletes
// the pack machinery. Depth-2 B reg sets (SE even kt / SO odd kt): step kt
// converts B(kt) (retired >=1 step ago => NO head wait), reloads the same
// set with B(kt+2); tail vmcnt(8) retires B(kt+1)+A(kt+1) with a full step
// of latency cover. A path = verified r6/r7 machinery (slot-XOR LDS dbuf,
// pre-swizzled-source global_load_lds, 0 bank conflicts). All issue groups
// sched_barrier-pinned (r9 lesson); ds-read pairs fenced so lgkm(2) is
// order-guaranteed.
// ---------------------------------------------------------------------------
__global__ __launch_bounds__(256, 2) void fused_z_decode_kernel(
    const u16* __restrict__ Xb,    // [512][4096] bf16
    const float* __restrict__ rot, // [8][4096][4096] fp32
    u16* __restrict__ Z,           // [8][512][4096] bf16
    const float* __restrict__ cw, const int* __restrict__ indices,
    const float* __restrict__ scales, u16* __restrict__ dec) {
  __shared__ char sA[16384];      // 2 bufs x [128][32] bf16 (slot-XOR)

  const int bid = blockIdx.x;
  if (bid < 256) {
    decode_body(bid, cw, indices, scales, dec);
    return;
  }
  const int lb = bid - 256;
  const int swz = ((lb & 7) << 7) | (lb >> 3);  // XCD-chunked (1024 % 8 == 0)
  const int t = swz >> 7;
  const int rem = swz & 127;
  const int nb = rem >> 2, mb = rem & 3;        // mb-sharers of B-panel adjacent
  const float* Bt = rot + ((size_t)t << 24);
  u16* Ct = Z + ((size_t)t << 21);
  const int aRow0 = mb << 7, bCol0 = nb << 7;
  const int tid = threadIdx.x;
  const int wv = tid >> 6, ln = tid & 63;
  const int lr = ln & 15, lk = ln >> 4;
  const int wr = wv >> 1, wc = wv & 1;

  fx4 acc[4][4] = {};

  // ---- A staging (verified r6/r7): source pre-swizzle, [128][32] per buf
  const u16* Asrc = Xb + (size_t)(aRow0 + (ln >> 2)) * 4096 +
                    (((ln & 3) ^ ((ln >> 3) & 3)) << 3);
  const int gr = (lr >> 1) & 3;
  const int aof = (wr * 64 + lr) * 64 + ((lk ^ gr) << 4);  // + m*1024

  // ---- B direct-to-frag: lane (lr,lk) reads rot[bCol0+wc*64+n*16+lr]
  //      [kt*32 + lk*8 .. +8] as two float4 per n-frag
  const float* Bfs = Bt + (size_t)(bCol0 + wc * 64 + lr) * 4096 + lk * 8;

#define STAGE_A_Z(dbuf, kofs)                                                 \
  _Pragma("unroll")                                                           \
  for (int c = 0; c < 2; ++c)                                                 \
    __builtin_amdgcn_global_load_lds(                                         \
        (gvoid*)(Asrc + (size_t)((c * 4 + wv) << 4) * 4096 + (kofs)),         \
        (lvoid*)(sA + (dbuf) * 8192 + c * 4096 + (wv << 10) + ln * 16),       \
        16, 0, 0)

#define LOADB_F(S, kt)                                                        \
  do {                                                                        \
    const float* bp_ = Bfs + (size_t)(kt) * 32;                               \
    S[0] = *(const float4*)(bp_);                                             \
    S[1] = *(const float4*)(bp_ + 4);                                         \
    S[2] = *(const float4*)(bp_ + 16 * 4096);                                 \
    S[3] = *(const float4*)(bp_ + 16 * 4096 + 4);                             \
    S[4] = *(const float4*)(bp_ + 32 * 4096);                                 \
    S[5] = *(const float4*)(bp_ + 32 * 4096 + 4);                             \
    S[6] = *(const float4*)(bp_ + 48 * 4096);                                 \
    S[7] = *(const float4*)(bp_ + 48 * 4096 + 4);                             \
  } while (0)

#define CVT_B(S)                                                              \
  do {                                                                        \
    bf[0][0] = cvt_pk_bf16(S[0].x, S[0].y);                                   \
    bf[0][1] = cvt_pk_bf16(S[0].z, S[0].w);                                   \
    bf[0][2] = cvt_pk_bf16(S[1].x, S[1].y);                                   \
    bf[0][3] = cvt_pk_bf16(S[1].z, S[1].w);                                   \
    bf[1][0] = cvt_pk_bf16(S[2].x, S[2].y);                                   \
    bf[1][1] = cvt_pk_bf16(S[2].z, S[2].w);                                   \
    bf[1][2] = cvt_pk_bf16(S[3].x, S[3].y);                                   \
    bf[1][3] = cvt_pk_bf16(S[3].z, S[3].w);                                   \
    bf[2][0] = cvt_pk_bf16(S[4].x, S[4].y);                                   \
    bf[2][1] = cvt_pk_bf16(S[4].z, S[4].w);                                   \
    bf[2][2] = cvt_pk_bf16(S[5].x, S[5].y);                                   \
    bf[2][3] = cvt_pk_bf16(S[5].z, S[5].w);                                   \
    bf[3][0] = cvt_pk_bf16(S[6].x, S[6].y);                                   \
    bf[3][1] = cvt_pk_bf16(S[6].z, S[6].w);                                   \
    bf[3][2] = cvt_pk_bf16(S[7].x, S[7].y);                                   \
    bf[3][3] = cvt_pk_bf16(S[7].z, S[7].w);                                   \
  } while (0)

#define MFMA_HALF(M0, M1)                                                     \
  do {                                                                        \
    __builtin_amdgcn_s_setprio(1);                                            \
    _Pragma("unroll")                                                         \
    for (int n = 0; n < 4; ++n) {                                             \
      MFMA_BF16_16x16x32(acc[M0][n], af[M0], bf[n]);                          \
      MFMA_BF16_16x16x32(acc[M1][n], af[M1], bf[n]);                          \
    }                                                                         \
    __builtin_amdgcn_s_setprio(0);                                            \
  } while (0)

// One K-step. d = LDS buf read; S = reg set holding B(kt) fp32 (retired),
// reloaded with B(kt+2). Tail vmcnt(8) retires B(kt+1)[8] + A(kt+1)[2].
#define STEP_Z(d, S, kt, DOSTAGE, DOLOAD, TAILW)                              \
  do {                                                                        \
    const char* pA_ = sA + (d) * 8192;                                        \
    af[0] = *(const u32x4*)(pA_ + aof);                                       \
    af[1] = *(const u32x4*)(pA_ + aof + 1024);                                \
    SFENCE();                                                                 \
    af[2] = *(const u32x4*)(pA_ + aof + 2048);                                \
    af[3] = *(const u32x4*)(pA_ + aof + 3072);                                \
    SFENCE();                                                                 \
    CVT_B(S);                                                                 \
    SFENCE();                                                                 \
    if (DOSTAGE) { STAGE_A_Z((d) ^ 1, ((kt) + 1) << 5); }                     \
    SFENCE();                                                                 \
    if (DOLOAD) { LOADB_F(S, (kt) + 2); }                                     \
    SFENCE();                                                                 \
    WAIT_LGKM2();                                                             \
    SFENCE();                                                                 \
    MFMA_HALF(0, 1);                                                          \
    WAIT_LGKM0();                                                             \
    SFENCE();                                                                 \
    MFMA_HALF(2, 3);                                                          \
    TAILW;                                                                    \
    BARRIER();                                                                \
  } while (0)

  u32x4 af[4], bf[4];
  float4 SE[8], SO[8];

  // ---- prologue: A(0)->buf0; B(0)->SE; B(1)->SO; vm8 retires A(0)+B(0) ----
  STAGE_A_Z(0, 0);
  SFENCE();
  LOADB_F(SE, 0);
  SFENCE();
  LOADB_F(SO, 1);
  SFENCE();
  WAIT_VM8();
  BARRIER();

  // steady: kt = 0..125 (even SE / odd SO), full stage+load
#pragma unroll 1
  for (int kt2 = 0; kt2 < 126; kt2 += 2) {
    STEP_Z(0, SE, kt2, true, true, WAIT_VM8());
    STEP_Z(1, SO, kt2 + 1, true, true, WAIT_VM8());
  }
  // kt = 126: stage A(127), no B load; drain all
  STEP_Z(0, SE, 126, true, false, WAIT_VM0());
  // kt = 127: compute only (no stage/load/barrier)
  {
    const char* pA_ = sA + 8192;
    af[0] = *(const u32x4*)(pA_ + aof);
    af[1] = *(const u32x4*)(pA_ + aof + 1024);
    SFENCE();
    af[2] = *(const u32x4*)(pA_ + aof + 2048);
    af[3] = *(const u32x4*)(pA_ + aof + 3072);
    SFENCE();
    CVT_B(SO);
    SFENCE();
    WAIT_LGKM2();
    SFENCE();
    MFMA_HALF(0, 1);
    WAIT_LGKM0();
    SFENCE();
    MFMA_HALF(2, 3);
  }

  // C/D layout: col = lane&15, row = (lane>>4)*4 + j
#pragma unroll
  for (int m = 0; m < 4; ++m) {
    const int r0 = aRow0 + wr * 64 + m * 16 + lk * 4;
#pragma unroll
    for (int n = 0; n < 4; ++n) {
      const int col = bCol0 + wc * 64 + n * 16 + lr;
#pragma unroll
      for (int j = 0; j < 4; ++j)
        Ct[(size_t)(r0 + j) * 4096 + col] = f2bf_rne(acc[m][n][j]);
    }
  }
#undef STAGE_A_Z
#undef LOADB_F
#undef CVT_B
#undef MFMA_HALF
#undef STEP_Z
}

// ---------------------------------------------------------------------------
// out[n, t*512+r] = sum_d z[t,n,d]*dec[t,r,d] + bias. 128x64 tile, BK=32.
// QUAD-buffered depth-3 pipeline (1 block/CU: no cross-block cover, ~2 full
// steps hide HBM latency). Counted vmcnt(6) steady. (Verified round 10.)
// ---------------------------------------------------------------------------
__global__ __launch_bounds__(256, 2) void gemm_out_kernel(
    const u16* __restrict__ Z,    // [8][512][4096]
    const u16* __restrict__ Dec,  // [8][512][4096]
    const float* __restrict__ bias,
    float* __restrict__ out) {    // [512][4096]
  __shared__ char sm[49152];      // 4 bufs x (A 8KB + B 4KB)
  const int lb = blockIdx.x;
  const int swz = ((lb & 7) << 5) | (lb >> 3);  // 256 % 8 == 0
  const int t = swz >> 5;
  const int rem = swz & 31;
  const int nb = rem >> 2, mb = rem & 3;
  const u16* At = Z + ((size_t)t << 21);
  const u16* Bt = Dec + ((size_t)t << 21);
  const int aRow0 = mb << 7, bCol0 = nb << 6;
  const int tid = threadIdx.x;
  const int wv = tid >> 6, ln = tid & 63;
  const int lr = ln & 15, lk = ln >> 4;
  const int wr = wv >> 1, wc = wv & 1;

  fx4 acc[4][2] = {};

  const int kswz = (((tid & 3) ^ ((tid >> 3) & 3)) << 3);
  const u16* Asrc = At + (size_t)(aRow0 + (tid >> 2)) * 4096 + kswz;
  const u16* Bsrc = Bt + (size_t)(bCol0 + (tid >> 2)) * 4096 + kswz;
  const int gr = (lr >> 1) & 3;
  const int aof = (wr * 64 + lr) * 64 + ((lk ^ gr) << 4);          // + m*1024
  const int bof = 8192 + (wc * 32 + lr) * 64 + ((lk ^ gr) << 4);   // + n*1024

#define STAGE_O(buf, kofs)                                                   \
  do {                                                                       \
    _Pragma("unroll")                                                        \
    for (int c = 0; c < 2; ++c)                                              \
      __builtin_amdgcn_global_load_lds(                                      \
          (gvoid*)(Asrc + (size_t)(c << 6) * 4096 + (kofs)),                 \
          (lvoid*)((buf) + c * 4096 + tid * 16), 16, 0, 0);                  \
    __builtin_amdgcn_global_load_lds((gvoid*)(Bsrc + (kofs)),                \
                                     (lvoid*)((buf) + 8192 + tid * 16), 16,  \
                                     0, 0);                                  \
  } while (0)

  char* b0 = sm;
  char* b1 = sm + 12288;
  char* b2 = sm + 24576;
  char* b3 = sm + 36864;
  STAGE_O(b0, 0);
  STAGE_O(b1, 32);
  STAGE_O(b2, 64);
  WAIT_VM6();                     // stage(0) complete; 1,2 in flight
  BARRIER();

#pragma unroll 1
  for (int kt = 0; kt < 128; ++kt) {
    if (kt + 3 < 128) STAGE_O(b3, (kt + 3) << 5);
    u32x4 af[4], bf[2];
#pragma unroll
    for (int m = 0; m < 4; ++m)
      af[m] = *(const u32x4*)(b0 + aof + m * 1024);
#pragma unroll
    for (int n = 0; n < 2; ++n)
      bf[n] = *(const u32x4*)(b0 + bof + n * 1024);
    WAIT_LGKM0();
    SFENCE();
#pragma unroll
    for (int m = 0; m < 4; ++m)
#pragma unroll
      for (int n = 0; n < 2; ++n)
        MFMA_BF16_16x16x32(acc[m][n], af[m], bf[n]);
    if (kt + 3 < 128) {
      WAIT_VM6();                 // stage(kt+1) done; kt+2, kt+3 in flight
    } else if (kt + 2 < 128) {
      WAIT_VM3();                 // kt = 125
    } else {
      WAIT_VM0();                 // kt = 126, 127
    }
    BARRIER();
    char* tmp = b0; b0 = b1; b1 = b2; b2 = b3; b3 = tmp;
  }

#pragma unroll
  for (int n = 0; n < 2; ++n) {
    const int colg = (t << 9) + bCol0 + wc * 32 + n * 16 + lr;
    const float bv = bias[colg];
#pragma unroll
    for (int m = 0; m < 4; ++m) {
      const int r0 = aRow0 + wr * 64 + m * 16 + lk * 4;
#pragma unroll
      for (int j = 0; j < 4; ++j)
        out[(size_t)(r0 + j) * 4096 + colg] = acc[m][n][j] + bv;
    }
  }
#undef STAGE_O
}

// ---------------------------------------------------------------------------
extern "C" void kernel_launch(void* const* d_in, const int* in_sizes, int n_in,
                              void* d_out, int out_size, void* d_ws, size_t ws_size,
                              hipStream_t stream) {
  const float* x       = (const float*)d_in[0];   // [512][4096]
  const float* cw      = (const float*)d_in[1];   // [16384][4096]
  const int*   indices = (const int*)d_in[2];     // [8][512][4]
  const float* rot     = (const float*)d_in[3];   // [8][4096][4096]
  const float* scales  = (const float*)d_in[4];   // [8]
  const float* bias    = (const float*)d_in[5];   // [4096]
  float* out = (float*)d_out;
  char* ws = (char*)d_ws;

  u16* xb  = (u16*)(ws);                          // 4 MiB
  u16* dec = (u16*)(ws + ((size_t)4 << 20));      // 32 MiB
  u16* z   = (u16*)(ws + ((size_t)36 << 20));     // 32 MiB

  cvtx_kernel<<<dim3(2048), dim3(256), 0, stream>>>(x, xb);
  fused_z_decode_kernel<<<dim3(1280), dim3(256), 0, stream>>>(
      xb, rot, z, cw, indices, scales, dec);
  gemm_out_kernel<<<dim3(256), dim3(256), 0, stream>>>(z, dec, bias, out);
}

// Round 12
// 289.131 us; speedup vs baseline: 2.1190x; 2.1190x over previous
//
#include <hip/hip_runtime.h>

typedef unsigned int uint32;
typedef unsigned short u16;
typedef float fx4 __attribute__((ext_vector_type(4)));
typedef uint32 u32x4 __attribute__((ext_vector_type(4)));
typedef uint32 u32x2 __attribute__((ext_vector_type(2)));

typedef const __attribute__((address_space(1))) void gvoid;
typedef __attribute__((address_space(3))) void lvoid;

#define MFMA_BF16_16x16x32(acc, a, b) \
  asm("v_mfma_f32_16x16x32_bf16 %0, %1, %2, %0" : "+v"(acc) : "v"(a), "v"(b))

#define WAIT_LGKM0() asm volatile("s_waitcnt lgkmcnt(0)" ::: "memory")
#define WAIT_LGKM4() asm volatile("s_waitcnt lgkmcnt(4)" ::: "memory")
#define WAIT_VM0()   asm volatile("s_waitcnt vmcnt(0)" ::: "memory")
#define WAIT_VM2()   asm volatile("s_waitcnt vmcnt(2)" ::: "memory")
#define WAIT_VM3()   asm volatile("s_waitcnt vmcnt(3)" ::: "memory")
#define WAIT_VM6()   asm volatile("s_waitcnt vmcnt(6)" ::: "memory")
#define WAIT_VM8()   asm volatile("s_waitcnt vmcnt(8)" ::: "memory")
#define WAIT_VM10()  asm volatile("s_waitcnt vmcnt(10)" ::: "memory")
#define SFENCE()     __builtin_amdgcn_sched_barrier(0)
#define BARRIER()    do { __builtin_amdgcn_s_barrier(); asm volatile("" ::: "memory"); } while (0)

__device__ __forceinline__ u16 f2bf_rne(float f) {
  uint32 u = __builtin_bit_cast(uint32, f);
  u += 0x7FFFu + ((u >> 16) & 1u);
  return (u16)(u >> 16);
}

__device__ __forceinline__ uint32 cvt_pk_bf16(float lo, float hi) {
  uint32 r;
  asm("v_cvt_pk_bf16_f32 %0, %1, %2" : "=v"(r) : "v"(lo), "v"(hi));
  return r;
}

// ---------------------------------------------------------------------------
// x (fp32) -> bf16
// ---------------------------------------------------------------------------
__global__ __launch_bounds__(256) void cvtx_kernel(const float* __restrict__ x,
                                                   u16* __restrict__ xb) {
  const int i = blockIdx.x * 256 + threadIdx.x;
  float4 v = ((const float4*)x)[i];
  ushort4 o;
  o.x = f2bf_rne(v.x);
  o.y = f2bf_rne(v.y);
  o.z = f2bf_rne(v.z);
  o.w = f2bf_rne(v.w);
  ((ushort4*)xb)[i] = o;
}

// ---------------------------------------------------------------------------
// decode body (512 threads): dec[t,r,:] = scales[t]*0.25*sum_k cw[idx,:]
// ---------------------------------------------------------------------------
__device__ __forceinline__ void decode_body(
    int bid, const float* __restrict__ cw, const int* __restrict__ indices,
    const float* __restrict__ scales, u16* __restrict__ dec) {
  const int tid = threadIdx.x;
#pragma unroll 1
  for (int rr = 0; rr < 16; ++rr) {
    const int row = bid * 16 + rr;       // t*512 + r
    const int t = row >> 9;
    const int* ip = indices + (size_t)row * 4;
    const float* c0 = cw + (size_t)ip[0] * 4096;
    const float* c1 = cw + (size_t)ip[1] * 4096;
    const float* c2 = cw + (size_t)ip[2] * 4096;
    const float* c3 = cw + (size_t)ip[3] * 4096;
    const float s = scales[t] * 0.25f;
    u16* orow = dec + (size_t)row * 4096;
#pragma unroll
    for (int j = 0; j < 2; ++j) {
      const int d = j * 2048 + tid * 4;
      float4 a = *(const float4*)(c0 + d);
      float4 b = *(const float4*)(c1 + d);
      float4 c = *(const float4*)(c2 + d);
      float4 e = *(const float4*)(c3 + d);
      ushort4 o;
      o.x = f2bf_rne((a.x + b.x + c.x + e.x) * s);
      o.y = f2bf_rne((a.y + b.y + c.y + e.y) * s);
      o.z = f2bf_rne((a.z + b.z + c.z + e.z) * s);
      o.w = f2bf_rne((a.w + b.w + c.w + e.w) * s);
      *(ushort4*)(orow + d) = o;
    }
  }
}

// ---------------------------------------------------------------------------
// Fused: blocks [0,256) decode; blocks [256,512) z[t] = x_bf16 @ rot[t]^T.
// GEMM: 256x256 tile, BK=32, 8 waves (2 wave-rows x 4 wave-cols), wave tile
// 128x64, acc[8][4] fx4 (128 VGPR). grid = 8t x 2mb x 16nb = 256 = 1/CU.
// LDS 96KB: A quad-buffered [256][32]bf16 (4 x 16KB, slot-XOR, staged via
// global_load_lds with pre-swizzled source), B double-buffered (2 x 16KB,
// reg-staged fp32 -> cvt_pk_bf16 -> swizzled ds_write, period-3 reg sets).
// Steady step kt: head-pack B(kt+1) (loaded 3 steps ago -> retired, NO wait)
// -> 12 ds_reads (pinned groups) -> stage A(kt+2) + load B(kt+4) ->
// lgkm(4) -> 16 MFMA -> lgkm(0) -> 16 MFMA -> vmcnt(10) [retires A(kt+1) +
// B(kt+2); keeps B(kt+3), A(kt+2), B(kt+4) in flight] -> barrier.
// All issue groups sched_barrier-pinned (r9 lesson).
// ---------------------------------------------------------------------------
__global__ __launch_bounds__(512, 2) void fused_z_decode_kernel(
    const u16* __restrict__ Xb,    // [512][4096] bf16
    const float* __restrict__ rot, // [8][4096][4096] fp32
    u16* __restrict__ Z,           // [8][512][4096] bf16
    const float* __restrict__ cw, const int* __restrict__ indices,
    const float* __restrict__ scales, u16* __restrict__ dec) {
  __shared__ char sA[65536];      // 4 bufs x [256 rows][64B]
  __shared__ char sB[32768];      // 2 bufs x [256 rows][64B]

  const int bid = blockIdx.x;
  if (bid < 256) {
    decode_body(bid, cw, indices, scales, dec);
    return;
  }
  const int lb = bid - 256;                      // [0,256)
  const int swz = ((lb & 7) << 5) | (lb >> 3);   // XCD-chunked, 256%8==0
  const int t = swz >> 5;
  const int rem = swz & 31;
  const int nb = rem >> 1, mb = rem & 1;
  const float* Bt = rot + ((size_t)t << 24);
  u16* Ct = Z + ((size_t)t << 21);
  const int aRow0 = mb << 8, bCol0 = nb << 8;
  const int tid = threadIdx.x;
  const int wv = tid >> 6, ln = tid & 63;
  const int lr = ln & 15, lk = ln >> 4;
  const int wr = wv >> 2, wc = wv & 3;

  fx4 acc[8][4] = {};

  // A staging: source chunk pre-swizzle (16B permute within 64B row)
  const u16* Asrc = Xb + (size_t)(aRow0 + (tid >> 2)) * 4096 +
                    (((tid & 3) ^ ((tid >> 3) & 3)) << 3);
  // B staging (coalesced): rows R0+8j, fp32 chunk cB
  const int R0 = wv * 32 + (ln >> 3);
  const int cB = ln & 7;
  const float* Bsrc = Bt + (size_t)(bCol0 + R0) * 4096 + cB * 4;
  const int bwr = R0 * 64 + ((((cB >> 1) ^ ((R0 >> 1) & 3)) << 4)) + ((cB & 1) << 3);
  // frag read offsets (slot-XOR folded into per-lane constant)
  const int gr = (lr >> 1) & 3;
  const int aof = (wr * 128 + lr) * 64 + ((lk ^ gr) << 4);  // + m*1024
  const int bof = (wc * 64 + lr) * 64 + ((lk ^ gr) << 4);   // + n*1024

#define STAGE_A(dbuf, kofs)                                                   \
  _Pragma("unroll")                                                           \
  for (int c = 0; c < 2; ++c)                                                 \
    __builtin_amdgcn_global_load_lds(                                         \
        (gvoid*)(Asrc + (size_t)(c * 128) * 4096 + (kofs)),                   \
        (lvoid*)(sA + (dbuf) * 16384 + c * 8192 + tid * 16), 16, 0, 0)

#define LOADB(S, kt)                                                          \
  do {                                                                        \
    const float* bp_ = Bsrc + (size_t)(kt) * 32;                              \
    S[0] = *(const float4*)(bp_);                                             \
    S[1] = *(const float4*)(bp_ + 8 * 4096);                                  \
    S[2] = *(const float4*)(bp_ + 16 * 4096);                                 \
    S[3] = *(const float4*)(bp_ + 24 * 4096);                                 \
  } while (0)

#define PACK_B(S, dst)                                                        \
  do {                                                                        \
    u32x2 w_;                                                                 \
    w_[0] = cvt_pk_bf16(S[0].x, S[0].y); w_[1] = cvt_pk_bf16(S[0].z, S[0].w); \
    *(u32x2*)((dst) + bwr) = w_;                                              \
    w_[0] = cvt_pk_bf16(S[1].x, S[1].y); w_[1] = cvt_pk_bf16(S[1].z, S[1].w); \
    *(u32x2*)((dst) + bwr + 512) = w_;                                        \
    w_[0] = cvt_pk_bf16(S[2].x, S[2].y); w_[1] = cvt_pk_bf16(S[2].z, S[2].w); \
    *(u32x2*)((dst) + bwr + 1024) = w_;                                       \
    w_[0] = cvt_pk_bf16(S[3].x, S[3].y); w_[1] = cvt_pk_bf16(S[3].z, S[3].w); \
    *(u32x2*)((dst) + bwr + 1536) = w_;                                       \
  } while (0)

#define MFMA_LO()                                                             \
  do {                                                                        \
    __builtin_amdgcn_s_setprio(1);                                            \
    _Pragma("unroll")                                                         \
    for (int m = 0; m < 4; ++m)                                               \
      _Pragma("unroll")                                                       \
      for (int n = 0; n < 4; ++n)                                             \
        MFMA_BF16_16x16x32(acc[m][n], af[m], bf[n]);                          \
    __builtin_amdgcn_s_setprio(0);                                            \
  } while (0)
#define MFMA_HI()                                                             \
  do {                                                                        \
    __builtin_amdgcn_s_setprio(1);                                            \
    _Pragma("unroll")                                                         \
    for (int m = 4; m < 8; ++m)                                               \
      _Pragma("unroll")                                                       \
      for (int n = 0; n < 4; ++n)                                             \
        MFMA_BF16_16x16x32(acc[m][n], af[m], bf[n]);                          \
    __builtin_amdgcn_s_setprio(0);                                            \
  } while (0)

// One K-step. A4 = kt&3, B2 = kt&1, S = sets[kt%3] (holds B(kt+1)).
#define STEP_Z(A4, B2, S, kt, DOSTAGE, DOLOAD, TAILW)                         \
  do {                                                                        \
    PACK_B(S, sB + ((B2) ^ 1) * 16384);                                       \
    SFENCE();                                                                 \
    {                                                                         \
      const char* pA_ = sA + (A4) * 16384;                                    \
      const char* pB_ = sB + (B2) * 16384;                                    \
      af[0] = *(const u32x4*)(pA_ + aof);                                     \
      af[1] = *(const u32x4*)(pA_ + aof + 1024);                              \
      af[2] = *(const u32x4*)(pA_ + aof + 2048);                              \
      af[3] = *(const u32x4*)(pA_ + aof + 3072);                              \
      bf[0] = *(const u32x4*)(pB_ + bof);                                     \
      bf[1] = *(const u32x4*)(pB_ + bof + 1024);                              \
      bf[2] = *(const u32x4*)(pB_ + bof + 2048);                              \
      bf[3] = *(const u32x4*)(pB_ + bof + 3072);                              \
      SFENCE();                                                               \
      if (DOSTAGE) { STAGE_A(((kt) + 2) & 3, ((kt) + 2) << 5); }              \
      SFENCE();                                                               \
      if (DOLOAD) { LOADB(S, (kt) + 4); }                                     \
      SFENCE();                                                               \
      af[4] = *(const u32x4*)(pA_ + aof + 4096);                              \
      af[5] = *(const u32x4*)(pA_ + aof + 5120);                              \
      af[6] = *(const u32x4*)(pA_ + aof + 6144);                              \
      af[7] = *(const u32x4*)(pA_ + aof + 7168);                              \
      SFENCE();                                                               \
    }                                                                         \
    WAIT_LGKM4();                                                             \
    SFENCE();                                                                 \
    MFMA_LO();                                                                \
    WAIT_LGKM0();                                                             \
    SFENCE();                                                                 \
    MFMA_HI();                                                                \
    TAILW;                                                                    \
    BARRIER();                                                                \
  } while (0)

  u32x4 af[8], bf[4];
  float4 s0[4], s1[4], s2[4];

  // ---- prologue ----
  STAGE_A(0, 0);                  // A(0) -> buf0
  STAGE_A(1, 1 << 5);             // A(1) -> buf1
  SFENCE();
  LOADB(s2, 0);                   // B(0) -> s2 (temp)
  SFENCE();
  WAIT_VM0();
  SFENCE();
  PACK_B(s2, sB);                 // B(0) -> sB buf0
  SFENCE();
  LOADB(s0, 1);                   // B(1) -> s0 (packed at step 0)
  SFENCE();
  LOADB(s1, 2);                   // B(2) -> s1
  SFENCE();
  LOADB(s2, 3);                   // B(3) -> s2
  SFENCE();
  WAIT_VM8();                     // B(1) retired; B(2),B(3) in flight
  WAIT_LGKM0();
  BARRIER();

  // ---- steady: kt = 0..119, period 12 (A mod 4, B mod 2, sets mod 3) ----
#pragma unroll 1
  for (int k0 = 0; k0 < 120; k0 += 12) {
    STEP_Z(0, 0, s0, k0 + 0, 1, 1, WAIT_VM10());
    STEP_Z(1, 1, s1, k0 + 1, 1, 1, WAIT_VM10());
    STEP_Z(2, 0, s2, k0 + 2, 1, 1, WAIT_VM10());
    STEP_Z(3, 1, s0, k0 + 3, 1, 1, WAIT_VM10());
    STEP_Z(0, 0, s1, k0 + 4, 1, 1, WAIT_VM10());
    STEP_Z(1, 1, s2, k0 + 5, 1, 1, WAIT_VM10());
    STEP_Z(2, 0, s0, k0 + 6, 1, 1, WAIT_VM10());
    STEP_Z(3, 1, s1, k0 + 7, 1, 1, WAIT_VM10());
    STEP_Z(0, 0, s2, k0 + 8, 1, 1, WAIT_VM10());
    STEP_Z(1, 1, s0, k0 + 9, 1, 1, WAIT_VM10());
    STEP_Z(2, 0, s1, k0 + 10, 1, 1, WAIT_VM10());
    STEP_Z(3, 1, s2, k0 + 11, 1, 1, WAIT_VM10());
  }
  // ---- epilogue: kt = 120..127 (FIFO-audited tails) ----
  STEP_Z(0, 0, s0, 120, 1, 1, WAIT_VM10());
  STEP_Z(1, 1, s1, 121, 1, 1, WAIT_VM10());
  STEP_Z(2, 0, s2, 122, 1, 1, WAIT_VM10());
  STEP_Z(3, 1, s0, 123, 1, 1, WAIT_VM10());
  STEP_Z(0, 0, s1, 124, 1, 0, WAIT_VM6());   // stage A(126); pack B(125)
  STEP_Z(1, 1, s2, 125, 1, 0, WAIT_VM2());   // stage A(127); pack B(126)
  STEP_Z(2, 0, s0, 126, 0, 0, WAIT_VM0());   // pack B(127)
  // kt = 127: compute only (A buf3, B buf1)
  {
    const char* pA_ = sA + 3 * 16384;
    const char* pB_ = sB + 1 * 16384;
    af[0] = *(const u32x4*)(pA_ + aof);
    af[1] = *(const u32x4*)(pA_ + aof + 1024);
    af[2] = *(const u32x4*)(pA_ + aof + 2048);
    af[3] = *(const u32x4*)(pA_ + aof + 3072);
    bf[0] = *(const u32x4*)(pB_ + bof);
    bf[1] = *(const u32x4*)(pB_ + bof + 1024);
    bf[2] = *(const u32x4*)(pB_ + bof + 2048);
    bf[3] = *(const u32x4*)(pB_ + bof + 3072);
    SFENCE();
    af[4] = *(const u32x4*)(pA_ + aof + 4096);
    af[5] = *(const u32x4*)(pA_ + aof + 5120);
    af[6] = *(const u32x4*)(pA_ + aof + 6144);
    af[7] = *(const u32x4*)(pA_ + aof + 7168);
    SFENCE();
    WAIT_LGKM4();
    SFENCE();
    MFMA_LO();
    WAIT_LGKM0();
    SFENCE();
    MFMA_HI();
  }

  // C/D layout: col = lane&15, row = (lane>>4)*4 + j
#pragma unroll
  for (int m = 0; m < 8; ++m) {
    const int r0 = aRow0 + wr * 128 + m * 16 + lk * 4;
#pragma unroll
    for (int n = 0; n < 4; ++n) {
      const int col = bCol0 + wc * 64 + n * 16 + lr;
#pragma unroll
      for (int j = 0; j < 4; ++j)
        Ct[(size_t)(r0 + j) * 4096 + col] = f2bf_rne(acc[m][n][j]);
    }
  }
#undef STAGE_A
#undef LOADB
#undef PACK_B
#undef MFMA_LO
#undef MFMA_HI
#undef STEP_Z
}

// ---------------------------------------------------------------------------
// out[n, t*512+r] = sum_d z[t,n,d]*dec[t,r,d] + bias. 128x64 tile, BK=32.
// QUAD-buffered depth-3 pipeline, counted vmcnt(6). (Verified round 10.)
// ---------------------------------------------------------------------------
__global__ __launch_bounds__(256, 2) void gemm_out_kernel(
    const u16* __restrict__ Z,    // [8][512][4096]
    const u16* __restrict__ Dec,  // [8][512][4096]
    const float* __restrict__ bias,
    float* __restrict__ out) {    // [512][4096]
  __shared__ char sm[49152];      // 4 bufs x (A 8KB + B 4KB)
  const int lb = blockIdx.x;
  const int swz = ((lb & 7) << 5) | (lb >> 3);  // 256 % 8 == 0
  const int t = swz >> 5;
  const int rem = swz & 31;
  const int nb = rem >> 2, mb = rem & 3;
  const u16* At = Z + ((size_t)t << 21);
  const u16* Bt = Dec + ((size_t)t << 21);
  const int aRow0 = mb << 7, bCol0 = nb << 6;
  const int tid = threadIdx.x;
  const int wv = tid >> 6, ln = tid & 63;
  const int lr = ln & 15, lk = ln >> 4;
  const int wr = wv >> 1, wc = wv & 1;

  fx4 acc[4][2] = {};

  const int kswz = (((tid & 3) ^ ((tid >> 3) & 3)) << 3);
  const u16* Asrc = At + (size_t)(aRow0 + (tid >> 2)) * 4096 + kswz;
  const u16* Bsrc = Bt + (size_t)(bCol0 + (tid >> 2)) * 4096 + kswz;
  const int gr = (lr >> 1) & 3;
  const int aof = (wr * 64 + lr) * 64 + ((lk ^ gr) << 4);          // + m*1024
  const int bof = 8192 + (wc * 32 + lr) * 64 + ((lk ^ gr) << 4);   // + n*1024

#define STAGE_O(buf, kofs)                                                   \
  do {                                                                       \
    _Pragma("unroll")                                                        \
    for (int c = 0; c < 2; ++c)                                              \
      __builtin_amdgcn_global_load_lds(                                      \
          (gvoid*)(Asrc + (size_t)(c << 6) * 4096 + (kofs)),                 \
          (lvoid*)((buf) + c * 4096 + tid * 16), 16, 0, 0);                  \
    __builtin_amdgcn_global_load_lds((gvoid*)(Bsrc + (kofs)),                \
                                     (lvoid*)((buf) + 8192 + tid * 16), 16,  \
                                     0, 0);                                  \
  } while (0)

  char* b0 = sm;
  char* b1 = sm + 12288;
  char* b2 = sm + 24576;
  char* b3 = sm + 36864;
  STAGE_O(b0, 0);
  STAGE_O(b1, 32);
  STAGE_O(b2, 64);
  WAIT_VM6();                     // stage(0) complete; 1,2 in flight
  BARRIER();

#pragma unroll 1
  for (int kt = 0; kt < 128; ++kt) {
    if (kt + 3 < 128) STAGE_O(b3, (kt + 3) << 5);
    u32x4 af[4], bf[2];
#pragma unroll
    for (int m = 0; m < 4; ++m)
      af[m] = *(const u32x4*)(b0 + aof + m * 1024);
#pragma unroll
    for (int n = 0; n < 2; ++n)
      bf[n] = *(const u32x4*)(b0 + bof + n * 1024);
    WAIT_LGKM0();
    SFENCE();
#pragma unroll
    for (int m = 0; m < 4; ++m)
#pragma unroll
      for (int n = 0; n < 2; ++n)
        MFMA_BF16_16x16x32(acc[m][n], af[m], bf[n]);
    if (kt + 3 < 128) {
      WAIT_VM6();                 // stage(kt+1) done; kt+2, kt+3 in flight
    } else if (kt + 2 < 128) {
      WAIT_VM3();                 // kt = 125
    } else {
      WAIT_VM0();                 // kt = 126, 127
    }
    BARRIER();
    char* tmp = b0; b0 = b1; b1 = b2; b2 = b3; b3 = tmp;
  }

#pragma unroll
  for (int n = 0; n < 2; ++n) {
    const int colg = (t << 9) + bCol0 + wc * 32 + n * 16 + lr;
    const float bv = bias[colg];
#pragma unroll
    for (int m = 0; m < 4; ++m) {
      const int r0 = aRow0 + wr * 64 + m * 16 + lk * 4;
#pragma unroll
      for (int j = 0; j < 4; ++j)
        out[(size_t)(r0 + j) * 4096 + colg] = acc[m][n][j] + bv;
    }
  }
#undef STAGE_O
}

// ---------------------------------------------------------------------------
extern "C" void kernel_launch(void* const* d_in, const int* in_sizes, int n_in,
                              void* d_out, int out_size, void* d_ws, size_t ws_size,
                              hipStream_t stream) {
  const float* x       = (const float*)d_in[0];   // [512][4096]
  const float* cw      = (const float*)d_in[1];   // [16384][4096]
  const int*   indices = (const int*)d_in[2];     // [8][512][4]
  const float* rot     = (const float*)d_in[3];   // [8][4096][4096]
  const float* scales  = (const float*)d_in[4];   // [8]
  const float* bias    = (const float*)d_in[5];   // [4096]
  float* out = (float*)d_out;
  char* ws = (char*)d_ws;

  u16* xb  = (u16*)(ws);                          // 4 MiB
  u16* dec = (u16*)(ws + ((size_t)4 << 20));      // 32 MiB
  u16* z   = (u16*)(ws + ((size_t)36 << 20));     // 32 MiB

  cvtx_kernel<<<dim3(2048), dim3(256), 0, stream>>>(x, xb);
  fused_z_decode_kernel<<<dim3(512), dim3(512), 0, stream>>>(
      xb, rot, z, cw, indices, scales, dec);
  gemm_out_kernel<<<dim3(256), dim3(256), 0, stream>>>(z, dec, bias, out);
}

// Round 13
// 285.929 us; speedup vs baseline: 2.1428x; 1.0112x over previous
//
#include <hip/hip_runtime.h>

typedef unsigned int uint32;
typedef unsigned short u16;
typedef float fx4 __attribute__((ext_vector_type(4)));
typedef uint32 u32x4 __attribute__((ext_vector_type(4)));

typedef const __attribute__((address_space(1))) void gvoid;
typedef __attribute__((address_space(3))) void lvoid;

#define MFMA_BF16_16x16x32(acc, a, b) \
  asm("v_mfma_f32_16x16x32_bf16 %0, %1, %2, %0" : "+v"(acc) : "v"(a), "v"(b))

#define WAIT_LGKM0() asm volatile("s_waitcnt lgkmcnt(0)" ::: "memory")
#define WAIT_VM0()   asm volatile("s_waitcnt vmcnt(0)" ::: "memory")
#define WAIT_VM3()   asm volatile("s_waitcnt vmcnt(3)" ::: "memory")
#define WAIT_VM4()   asm volatile("s_waitcnt vmcnt(4)" ::: "memory")
#define WAIT_VM6()   asm volatile("s_waitcnt vmcnt(6)" ::: "memory")
#define WAIT_VM8()   asm volatile("s_waitcnt vmcnt(8)" ::: "memory")
#define WAIT_VM10()  asm volatile("s_waitcnt vmcnt(10)" ::: "memory")
#define SFENCE()     __builtin_amdgcn_sched_barrier(0)
#define BARRIER()    do { __builtin_amdgcn_s_barrier(); asm volatile("" ::: "memory"); } while (0)
#define NOWAIT()     do { } while (0)

__device__ __forceinline__ u16 f2bf_rne(float f) {
  uint32 u = __builtin_bit_cast(uint32, f);
  u += 0x7FFFu + ((u >> 16) & 1u);
  return (u16)(u >> 16);
}

__device__ __forceinline__ uint32 cvt_pk_bf16(float lo, float hi) {
  uint32 r;
  asm("v_cvt_pk_bf16_f32 %0, %1, %2" : "=v"(r) : "v"(lo), "v"(hi));
  return r;
}

// ---------------------------------------------------------------------------
// x (fp32) -> bf16
// ---------------------------------------------------------------------------
__global__ __launch_bounds__(256) void cvtx_kernel(const float* __restrict__ x,
                                                   u16* __restrict__ xb) {
  const int i = blockIdx.x * 256 + threadIdx.x;
  float4 v = ((const float4*)x)[i];
  ushort4 o;
  o.x = f2bf_rne(v.x);
  o.y = f2bf_rne(v.y);
  o.z = f2bf_rne(v.z);
  o.w = f2bf_rne(v.w);
  ((ushort4*)xb)[i] = o;
}

// ---------------------------------------------------------------------------
// decode: dec[t,r,d] = scales[t]*0.25 * sum_k cw[idx[t,r,k], d]  (bf16)
// 4096 blocks (one row each) x 256 threads: memory-bound, full occupancy.
// ---------------------------------------------------------------------------
__global__ __launch_bounds__(256) void decode_kernel(
    const float* __restrict__ cw, const int* __restrict__ indices,
    const float* __restrict__ scales, u16* __restrict__ dec) {
  const int row = blockIdx.x;      // t*512 + r
  const int t = row >> 9;
  const int* ip = indices + (size_t)row * 4;
  const float* c0 = cw + (size_t)ip[0] * 4096;
  const float* c1 = cw + (size_t)ip[1] * 4096;
  const float* c2 = cw + (size_t)ip[2] * 4096;
  const float* c3 = cw + (size_t)ip[3] * 4096;
  const float s = scales[t] * 0.25f;
  u16* orow = dec + (size_t)row * 4096;
  const int tid = threadIdx.x;
#pragma unroll
  for (int j = 0; j < 4; ++j) {
    const int d = j * 1024 + tid * 4;
    float4 a = *(const float4*)(c0 + d);
    float4 b = *(const float4*)(c1 + d);
    float4 c = *(const float4*)(c2 + d);
    float4 e = *(const float4*)(c3 + d);
    ushort4 o;
    o.x = f2bf_rne((a.x + b.x + c.x + e.x) * s);
    o.y = f2bf_rne((a.y + b.y + c.y + e.y) * s);
    o.z = f2bf_rne((a.z + b.z + c.z + e.z) * s);
    o.w = f2bf_rne((a.w + b.w + c.w + e.w) * s);
    *(ushort4*)(orow + d) = o;
  }
}

// ---------------------------------------------------------------------------
// gemm_z: z[t] = x_bf16 @ rot[t]^T.  256x256 tile, BK=64, 8 waves (2x4),
// wave tile 128x64, acc[8][4] (128 VGPR). 1 block/CU, LDS 128 KB.
// 4 quadrant-phases per K-tile (template: issue -> barrier -> lgkm0 ->
// setprio + 16 MFMA -> barrier). B (fp32 rot) reg-staged slice-per-phase:
// phase p packs B(kt+1) slice p (retired, NO wait beyond counted head) and
// reloads the same regs with B(kt+2) slice p. A staged p0 via 4
// global_load_lds (source chunk pre-swizzled). Slot-XOR (8 slots/128B row)
// on both tiles -> conflict-free ds_read_b128. Counted waits (FIFO-audited):
// steady p0 vm6, p1-p3 vm10, tail-of-iter vm8; never 0 until epilogue.
// ---------------------------------------------------------------------------
__global__ __launch_bounds__(512, 2) void gemm_z_kernel(
    const u16* __restrict__ Xb,    // [512][4096] bf16
    const float* __restrict__ rot, // [8][4096][4096] fp32
    u16* __restrict__ Z) {         // [8][512][4096] bf16
  __shared__ char sA[65536];       // 2 bufs x [256 rows][128B] (slot-XOR)
  __shared__ char sB[65536];

  const int lb = blockIdx.x;
  const int swz = ((lb & 7) << 5) | (lb >> 3);   // XCD-chunked, 256%8==0
  const int t = swz >> 5;
  const int rem = swz & 31;
  const int nb = rem >> 1, mb = rem & 1;         // mb-sharers adjacent
  const float* Bt = rot + ((size_t)t << 24);
  u16* Ct = Z + ((size_t)t << 21);
  const int aRow0 = mb << 8, bCol0 = nb << 8;
  const int tid = threadIdx.x;
  const int wv = tid >> 6, ln = tid & 63;
  const int lr = ln & 15, lk = ln >> 4;
  const int wr = wv >> 2, wc = wv & 3;

  fx4 acc[8][4] = {};

  // A stage: thread -> row (tid>>3) (+64/slice), 16B chunk (tid&7), source
  // chunk pre-swizzled by (row&7); dest linear (= tid*16 within slice).
  const u16* Asrc = Xb + (size_t)(aRow0 + (tid >> 3)) * 4096 +
                    (((tid & 7) ^ ((tid >> 3) & 7)) << 3);
  // B loads: same row map, 8 contiguous fp32 per thread (two float4).
  const float* Bsrc = Bt + (size_t)(bCol0 + (tid >> 3)) * 4096 + ((tid & 7) << 3);
  // packed write: one swizzled 16B slot per thread per slice
  const int bwr = (tid >> 3) * 128 + (((tid & 7) ^ ((tid >> 3) & 7)) << 4);
  // frag read bases: chunk(ks) = ks*4+lk, XOR (lr&7) per-lane constant
  const int cs0 = (lk ^ (lr & 7)) << 4;
  const int cs1 = ((4 + lk) ^ (lr & 7)) << 4;
  const int aB = (wr * 128 + lr) * 128;  // + MH*8192 + m*2048 + cs
  const int bB = (wc * 64 + lr) * 128;   // + NH*4096 + n*2048 + cs

#define STAGE_A4(DB, KT)                                                      \
  _Pragma("unroll")                                                           \
  for (int c = 0; c < 4; ++c)                                                 \
    __builtin_amdgcn_global_load_lds(                                         \
        (gvoid*)(Asrc + (size_t)(c << 6) * 4096 + ((KT) << 6)),               \
        (lvoid*)(sA + (DB) * 32768 + (c << 13) + (wv << 10) + ln * 16),       \
        16, 0, 0)

#define LOADB_S(KT, SL)                                                       \
  do {                                                                        \
    const float* bp_ = Bsrc + (size_t)((SL) << 6) * 4096 + ((KT) << 6);       \
    S[2 * (SL)] = *(const float4*)(bp_);                                      \
    S[2 * (SL) + 1] = *(const float4*)(bp_ + 4);                              \
  } while (0)

#define PACK_S(DSTB, SL)                                                      \
  do {                                                                        \
    u32x4 w_;                                                                 \
    w_[0] = cvt_pk_bf16(S[2 * (SL)].x, S[2 * (SL)].y);                        \
    w_[1] = cvt_pk_bf16(S[2 * (SL)].z, S[2 * (SL)].w);                        \
    w_[2] = cvt_pk_bf16(S[2 * (SL) + 1].x, S[2 * (SL) + 1].y);                \
    w_[3] = cvt_pk_bf16(S[2 * (SL) + 1].z, S[2 * (SL) + 1].w);                \
    *(u32x4*)((DSTB) + ((SL) << 13) + bwr) = w_;                              \
  } while (0)

#define READS_Q(D, MH, NH)                                                    \
  do {                                                                        \
    const char* pA_ = sA + (D) * 32768 + ((MH) << 13) + aB;                   \
    const char* pB_ = sB + (D) * 32768 + ((NH) << 12) + bB;                   \
    af[0][0] = *(const u32x4*)(pA_ + cs0);                                    \
    af[0][1] = *(const u32x4*)(pA_ + cs1);                                    \
    af[1][0] = *(const u32x4*)(pA_ + 2048 + cs0);                             \
    af[1][1] = *(const u32x4*)(pA_ + 2048 + cs1);                             \
    af[2][0] = *(const u32x4*)(pA_ + 4096 + cs0);                             \
    af[2][1] = *(const u32x4*)(pA_ + 4096 + cs1);                             \
    af[3][0] = *(const u32x4*)(pA_ + 6144 + cs0);                             \
    af[3][1] = *(const u32x4*)(pA_ + 6144 + cs1);                             \
    bf[0][0] = *(const u32x4*)(pB_ + cs0);                                    \
    bf[0][1] = *(const u32x4*)(pB_ + cs1);                                    \
    bf[1][0] = *(const u32x4*)(pB_ + 2048 + cs0);                             \
    bf[1][1] = *(const u32x4*)(pB_ + 2048 + cs1);                             \
  } while (0)

#define MFMA_Q(MH, NH)                                                        \
  do {                                                                        \
    __builtin_amdgcn_s_setprio(1);                                            \
    _Pragma("unroll")                                                         \
    for (int m = 0; m < 4; ++m)                                               \
      _Pragma("unroll")                                                       \
      for (int n = 0; n < 2; ++n) {                                           \
        MFMA_BF16_16x16x32(acc[(MH) * 4 + m][(NH) * 2 + n], af[m][0],         \
                           bf[n][0]);                                         \
        MFMA_BF16_16x16x32(acc[(MH) * 4 + m][(NH) * 2 + n], af[m][1],         \
                           bf[n][1]);                                         \
      }                                                                       \
    __builtin_amdgcn_s_setprio(0);                                            \
  } while (0)

#define PHASE_Z(D, MH, NH, SL, HV, DOPACK, DOSTAGE, DOLOAD, KT, TV)           \
  do {                                                                        \
    HV;                                                                       \
    SFENCE();                                                                 \
    if (DOPACK) { PACK_S(sB + ((D) ^ 1) * 32768, SL); }                       \
    SFENCE();                                                                 \
    READS_Q(D, MH, NH);                                                       \
    SFENCE();                                                                 \
    if (DOSTAGE) { STAGE_A4((D) ^ 1, (KT) + 1); }                             \
    SFENCE();                                                                 \
    if (DOLOAD) { LOADB_S((KT) + 2, SL); }                                    \
    SFENCE();                                                                 \
    BARRIER();                                                                \
    WAIT_LGKM0();                                                             \
    SFENCE();                                                                 \
    MFMA_Q(MH, NH);                                                           \
    TV;                                                                       \
    BARRIER();                                                                \
  } while (0)

  u32x4 af[4][2], bf[2][2];
  float4 S[8];

  // ---- prologue: A(0)->bufA0; B(0)->S->pack->bufB0; B(1)->S in flight ----
  STAGE_A4(0, 0);
  SFENCE();
  LOADB_S(0, 0); LOADB_S(0, 1); LOADB_S(0, 2); LOADB_S(0, 3);
  SFENCE();
  WAIT_VM0();
  SFENCE();
  PACK_S(sB, 0); PACK_S(sB, 1); PACK_S(sB, 2); PACK_S(sB, 3);
  SFENCE();
  LOADB_S(1, 0); LOADB_S(1, 1); LOADB_S(1, 2); LOADB_S(1, 3);
  SFENCE();
  WAIT_LGKM0();
  BARRIER();
  // in flight: B(1) x8. Steady invariant entering iter kt: B(kt+1) x8.

  // ---- steady iters kt = 0..61: pack B(kt+1), stage A(kt+1), load B(kt+2)
#pragma unroll 1
  for (int kt = 0; kt < 62; ++kt) {
    const int d = kt & 1;
    PHASE_Z(d, 0, 0, 0, WAIT_VM6(),  1, 1, 1, kt, NOWAIT());
    PHASE_Z(d, 0, 1, 1, WAIT_VM10(), 1, 0, 1, kt, NOWAIT());
    PHASE_Z(d, 1, 0, 2, WAIT_VM10(), 1, 0, 1, kt, NOWAIT());
    PHASE_Z(d, 1, 1, 3, WAIT_VM10(), 1, 0, 1, kt, WAIT_VM8());
  }
  // ---- kt = 62: pack B(63), stage A(63), no loads; drain tails ----
  PHASE_Z(0, 0, 0, 0, WAIT_VM6(), 1, 1, 0, 62, NOWAIT());
  PHASE_Z(0, 0, 1, 1, WAIT_VM8(), 1, 0, 0, 62, NOWAIT());
  PHASE_Z(0, 1, 0, 2, WAIT_VM6(), 1, 0, 0, 62, NOWAIT());
  PHASE_Z(0, 1, 1, 3, WAIT_VM4(), 1, 0, 0, 62, WAIT_VM0());
  // ---- kt = 63: compute only ----
  PHASE_Z(1, 0, 0, 0, NOWAIT(), 0, 0, 0, 63, NOWAIT());
  PHASE_Z(1, 0, 1, 1, NOWAIT(), 0, 0, 0, 63, NOWAIT());
  PHASE_Z(1, 1, 0, 2, NOWAIT(), 0, 0, 0, 63, NOWAIT());
  PHASE_Z(1, 1, 1, 3, NOWAIT(), 0, 0, 0, 63, NOWAIT());

  // C/D layout: col = lane&15, row = (lane>>4)*4 + j
#pragma unroll
  for (int m = 0; m < 8; ++m) {
    const int r0 = aRow0 + wr * 128 + m * 16 + lk * 4;
#pragma unroll
    for (int n = 0; n < 4; ++n) {
      const int col = bCol0 + wc * 64 + n * 16 + lr;
#pragma unroll
      for (int j = 0; j < 4; ++j)
        Ct[(size_t)(r0 + j) * 4096 + col] = f2bf_rne(acc[m][n][j]);
    }
  }
#undef STAGE_A4
#undef LOADB_S
#undef PACK_S
#undef READS_Q
#undef MFMA_Q
#undef PHASE_Z
}

// ---------------------------------------------------------------------------
// gemm_out SPLIT-K=2: partial[s][n, t*512+r] = sum_{d in half s} z*dec.
// 512 blocks (2 splits x 256), 128x64 tile, 64 K-steps each. Quad-buffered
// depth-3 counted-vmcnt pipeline (verified r10). Slot-XOR swizzle.
// ---------------------------------------------------------------------------
__global__ __launch_bounds__(256, 2) void gemm_out_kernel(
    const u16* __restrict__ Z,    // [8][512][4096]
    const u16* __restrict__ Dec,  // [8][512][4096]
    float* __restrict__ part) {   // [2][512][4096]
  __shared__ char sm[49152];      // 4 bufs x (A 8KB + B 4KB)
  const int lb = blockIdx.x;
  const int sp = lb >> 8;                       // K split 0/1
  const int ls = lb & 255;
  const int swz = ((ls & 7) << 5) | (ls >> 3);  // 256 % 8 == 0
  const int t = swz >> 5;
  const int rem = swz & 31;
  const int nb = rem >> 2, mb = rem & 3;
  const u16* At = Z + ((size_t)t << 21);
  const u16* Bt = Dec + ((size_t)t << 21);
  float* po = part + (size_t)sp * (512 * 4096);
  const int aRow0 = mb << 7, bCol0 = nb << 6;
  const int KS = sp << 11;                      // element offset of K half
  const int tid = threadIdx.x;
  const int wv = tid >> 6, ln = tid & 63;
  const int lr = ln & 15, lk = ln >> 4;
  const int wr = wv >> 1, wc = wv & 1;

  fx4 acc[4][2] = {};

  const int kswz = (((tid & 3) ^ ((tid >> 3) & 3)) << 3);
  const u16* Asrc = At + (size_t)(aRow0 + (tid >> 2)) * 4096 + KS + kswz;
  const u16* Bsrc = Bt + (size_t)(bCol0 + (tid >> 2)) * 4096 + KS + kswz;
  const int gr = (lr >> 1) & 3;
  const int aof = (wr * 64 + lr) * 64 + ((lk ^ gr) << 4);          // + m*1024
  const int bof = 8192 + (wc * 32 + lr) * 64 + ((lk ^ gr) << 4);   // + n*1024

#define STAGE_O(buf, kofs)                                                   \
  do {                                                                       \
    _Pragma("unroll")                                                        \
    for (int c = 0; c < 2; ++c)                                              \
      __builtin_amdgcn_global_load_lds(                                      \
          (gvoid*)(Asrc + (size_t)(c << 6) * 4096 + (kofs)),                 \
          (lvoid*)((buf) + c * 4096 + tid * 16), 16, 0, 0);                  \
    __builtin_amdgcn_global_load_lds((gvoid*)(Bsrc + (kofs)),                \
                                     (lvoid*)((buf) + 8192 + tid * 16), 16,  \
                                     0, 0);                                  \
  } while (0)

  char* b0 = sm;
  char* b1 = sm + 12288;
  char* b2 = sm + 24576;
  char* b3 = sm + 36864;
  STAGE_O(b0, 0);
  STAGE_O(b1, 32);
  STAGE_O(b2, 64);
  WAIT_VM6();                     // stage(0) complete; 1,2 in flight
  BARRIER();

#pragma unroll 1
  for (int kt = 0; kt < 64; ++kt) {
    if (kt + 3 < 64) STAGE_O(b3, (kt + 3) << 5);
    u32x4 af[4], bf[2];
#pragma unroll
    for (int m = 0; m < 4; ++m)
      af[m] = *(const u32x4*)(b0 + aof + m * 1024);
#pragma unroll
    for (int n = 0; n < 2; ++n)
      bf[n] = *(const u32x4*)(b0 + bof + n * 1024);
    WAIT_LGKM0();
    SFENCE();
#pragma unroll
    for (int m = 0; m < 4; ++m)
#pragma unroll
      for (int n = 0; n < 2; ++n)
        MFMA_BF16_16x16x32(acc[m][n], af[m], bf[n]);
    if (kt + 3 < 64) {
      WAIT_VM6();                 // stage(kt+1) done; kt+2, kt+3 in flight
    } else if (kt + 2 < 64) {
      WAIT_VM3();
    } else {
      WAIT_VM0();
    }
    BARRIER();
    char* tmp = b0; b0 = b1; b1 = b2; b2 = b3; b3 = tmp;
  }

#pragma unroll
  for (int n = 0; n < 2; ++n) {
    const int colg = (t << 9) + bCol0 + wc * 32 + n * 16 + lr;
#pragma unroll
    for (int m = 0; m < 4; ++m) {
      const int r0 = aRow0 + wr * 64 + m * 16 + lk * 4;
#pragma unroll
      for (int j = 0; j < 4; ++j)
        po[(size_t)(r0 + j) * 4096 + colg] = acc[m][n][j];
    }
  }
#undef STAGE_O
}

// ---------------------------------------------------------------------------
// combine: out = part0 + part1 + bias. 2048 blocks x 256 x float4.
// ---------------------------------------------------------------------------
__global__ __launch_bounds__(256) void combine_kernel(
    const float* __restrict__ p0, const float* __restrict__ p1,
    const float* __restrict__ bias, float* __restrict__ out) {
  const int i = blockIdx.x * 256 + threadIdx.x;
  float4 a = ((const float4*)p0)[i];
  float4 b = ((const float4*)p1)[i];
  float4 bv = ((const float4*)bias)[i & 1023];
  float4 o;
  o.x = a.x + b.x + bv.x;
  o.y = a.y + b.y + bv.y;
  o.z = a.z + b.z + bv.z;
  o.w = a.w + b.w + bv.w;
  ((float4*)out)[i] = o;
}

// ---------------------------------------------------------------------------
extern "C" void kernel_launch(void* const* d_in, const int* in_sizes, int n_in,
                              void* d_out, int out_size, void* d_ws, size_t ws_size,
                              hipStream_t stream) {
  const float* x       = (const float*)d_in[0];   // [512][4096]
  const float* cw      = (const float*)d_in[1];   // [16384][4096]
  const int*   indices = (const int*)d_in[2];     // [8][512][4]
  const float* rot     = (const float*)d_in[3];   // [8][4096][4096]
  const float* scales  = (const float*)d_in[4];   // [8]
  const float* bias    = (const float*)d_in[5];   // [4096]
  float* out = (float*)d_out;
  char* ws = (char*)d_ws;

  u16*   xb   = (u16*)(ws);                         // 4 MiB
  u16*   dec  = (u16*)(ws + ((size_t)4 << 20));     // 32 MiB
  u16*   z    = (u16*)(ws + ((size_t)36 << 20));    // 32 MiB
  float* part = (float*)(ws + ((size_t)68 << 20));  // 16 MiB (2 x 8 MiB)

  decode_kernel<<<dim3(4096), dim3(256), 0, stream>>>(cw, indices, scales, dec);
  cvtx_kernel<<<dim3(2048), dim3(256), 0, stream>>>(x, xb);
  gemm_z_kernel<<<dim3(256), dim3(512), 0, stream>>>(xb, rot, z);
  gemm_out_kernel<<<dim3(512), dim3(256), 0, stream>>>(z, dec, part);
  combine_kernel<<<dim3(2048), dim3(256), 0, stream>>>(
      part, part + (size_t)512 * 4096, bias, out);
}

// Round 14
// 279.361 us; speedup vs baseline: 2.1932x; 1.0235x over previous
//
#include <hip/hip_runtime.h>

typedef unsigned int uint32;
typedef unsigned short u16;
typedef float fx4 __attribute__((ext_vector_type(4)));
typedef uint32 u32x4 __attribute__((ext_vector_type(4)));

typedef const __attribute__((address_space(1))) void gvoid;
typedef __attribute__((address_space(3))) void lvoid;

#define MFMA_BF16_16x16x32(acc, a, b) \
  asm("v_mfma_f32_16x16x32_bf16 %0, %1, %2, %0" : "+v"(acc) : "v"(a), "v"(b))

#define WAIT_LGKM0() asm volatile("s_waitcnt lgkmcnt(0)" ::: "memory")
#define WAIT_VM0()   asm volatile("s_waitcnt vmcnt(0)" ::: "memory")
#define WAIT_VM3()   asm volatile("s_waitcnt vmcnt(3)" ::: "memory")
#define WAIT_VM4()   asm volatile("s_waitcnt vmcnt(4)" ::: "memory")
#define WAIT_VM6()   asm volatile("s_waitcnt vmcnt(6)" ::: "memory")
#define WAIT_VM8()   asm volatile("s_waitcnt vmcnt(8)" ::: "memory")
#define WAIT_VM10()  asm volatile("s_waitcnt vmcnt(10)" ::: "memory")
#define SFENCE()     __builtin_amdgcn_sched_barrier(0)
#define BARRIER()    do { __builtin_amdgcn_s_barrier(); asm volatile("" ::: "memory"); } while (0)
#define NOWAIT()     do { } while (0)

__device__ __forceinline__ u16 f2bf_rne(float f) {
  uint32 u = __builtin_bit_cast(uint32, f);
  u += 0x7FFFu + ((u >> 16) & 1u);
  return (u16)(u >> 16);
}

__device__ __forceinline__ uint32 cvt_pk_bf16(float lo, float hi) {
  uint32 r;
  asm("v_cvt_pk_bf16_f32 %0, %1, %2" : "=v"(r) : "v"(lo), "v"(hi));
  return r;
}

// ---------------------------------------------------------------------------
// x (fp32) -> bf16
// ---------------------------------------------------------------------------
__global__ __launch_bounds__(256) void cvtx_kernel(const float* __restrict__ x,
                                                   u16* __restrict__ xb) {
  const int i = blockIdx.x * 256 + threadIdx.x;
  float4 v = ((const float4*)x)[i];
  ushort4 o;
  o.x = f2bf_rne(v.x);
  o.y = f2bf_rne(v.y);
  o.z = f2bf_rne(v.z);
  o.w = f2bf_rne(v.w);
  ((ushort4*)xb)[i] = o;
}

// ---------------------------------------------------------------------------
// decode: dec[t,r,d] = scales[t]*0.25 * sum_k cw[idx[t,r,k], d]  (bf16)
// ---------------------------------------------------------------------------
__global__ __launch_bounds__(256) void decode_kernel(
    const float* __restrict__ cw, const int* __restrict__ indices,
    const float* __restrict__ scales, u16* __restrict__ dec) {
  const int row = blockIdx.x;      // t*512 + r
  const int t = row >> 9;
  const int* ip = indices + (size_t)row * 4;
  const float* c0 = cw + (size_t)ip[0] * 4096;
  const float* c1 = cw + (size_t)ip[1] * 4096;
  const float* c2 = cw + (size_t)ip[2] * 4096;
  const float* c3 = cw + (size_t)ip[3] * 4096;
  const float s = scales[t] * 0.25f;
  u16* orow = dec + (size_t)row * 4096;
  const int tid = threadIdx.x;
#pragma unroll
  for (int j = 0; j < 4; ++j) {
    const int d = j * 1024 + tid * 4;
    float4 a = *(const float4*)(c0 + d);
    float4 b = *(const float4*)(c1 + d);
    float4 c = *(const float4*)(c2 + d);
    float4 e = *(const float4*)(c3 + d);
    ushort4 o;
    o.x = f2bf_rne((a.x + b.x + c.x + e.x) * s);
    o.y = f2bf_rne((a.y + b.y + c.y + e.y) * s);
    o.z = f2bf_rne((a.z + b.z + c.z + e.z) * s);
    o.w = f2bf_rne((a.w + b.w + c.w + e.w) * s);
    *(ushort4*)(orow + d) = o;
  }
}

// ---------------------------------------------------------------------------
// gemm_z: z[t] = x_bf16 @ rot[t]^T.  256x256 tile, BK=64, 8 waves (2x4),
// wave tile 128x64, acc[8][4]. 1 block/CU, LDS 128 KB. 4 quadrant-phases per
// K-tile in SNAKE order (0,0)->(1,0)->(1,1)->(0,1): each transition reuses
// one operand half already in registers, so ds_reads per K-tile drop
// 48 -> 32 b128 (r13 re-read both halves every phase -> LDS-issue-bound).
// Waits/stage/load positions and counts IDENTICAL to r13 (audit carries).
// ---------------------------------------------------------------------------
__global__ __launch_bounds__(512, 2) void gemm_z_kernel(
    const u16* __restrict__ Xb,    // [512][4096] bf16
    const float* __restrict__ rot, // [8][4096][4096] fp32
    u16* __restrict__ Z) {         // [8][512][4096] bf16
  __shared__ char sA[65536];       // 2 bufs x [256 rows][128B] (slot-XOR)
  __shared__ char sB[65536];

  const int lb = blockIdx.x;
  const int swz = ((lb & 7) << 5) | (lb >> 3);   // XCD-chunked, 256%8==0
  const int t = swz >> 5;
  const int rem = swz & 31;
  const int nb = rem >> 1, mb = rem & 1;         // mb-sharers adjacent
  const float* Bt = rot + ((size_t)t << 24);
  u16* Ct = Z + ((size_t)t << 21);
  const int aRow0 = mb << 8, bCol0 = nb << 8;
  const int tid = threadIdx.x;
  const int wv = tid >> 6, ln = tid & 63;
  const int lr = ln & 15, lk = ln >> 4;
  const int wr = wv >> 2, wc = wv & 3;

  fx4 acc[8][4] = {};

  const u16* Asrc = Xb + (size_t)(aRow0 + (tid >> 3)) * 4096 +
                    (((tid & 7) ^ ((tid >> 3) & 7)) << 3);
  const float* Bsrc = Bt + (size_t)(bCol0 + (tid >> 3)) * 4096 + ((tid & 7) << 3);
  const int bwr = (tid >> 3) * 128 + (((tid & 7) ^ ((tid >> 3) & 7)) << 4);
  const int cs0 = (lk ^ (lr & 7)) << 4;
  const int cs1 = ((4 + lk) ^ (lr & 7)) << 4;
  const int aB = (wr * 128 + lr) * 128;  // + MH*8192 + m*2048 + cs
  const int bB = (wc * 64 + lr) * 128;   // + NH*4096 + n*2048 + cs

#define STAGE_A4(DB, KT)                                                      \
  _Pragma("unroll")                                                           \
  for (int c = 0; c < 4; ++c)                                                 \
    __builtin_amdgcn_global_load_lds(                                         \
        (gvoid*)(Asrc + (size_t)(c << 6) * 4096 + ((KT) << 6)),               \
        (lvoid*)(sA + (DB) * 32768 + (c << 13) + (wv << 10) + ln * 16),       \
        16, 0, 0)

#define LOADB_S(KT, SL)                                                       \
  do {                                                                        \
    const float* bp_ = Bsrc + (size_t)((SL) << 6) * 4096 + ((KT) << 6);       \
    S[2 * (SL)] = *(const float4*)(bp_);                                      \
    S[2 * (SL) + 1] = *(const float4*)(bp_ + 4);                              \
  } while (0)

#define PACK_S(DSTB, SL)                                                      \
  do {                                                                        \
    u32x4 w_;                                                                 \
    w_[0] = cvt_pk_bf16(S[2 * (SL)].x, S[2 * (SL)].y);                        \
    w_[1] = cvt_pk_bf16(S[2 * (SL)].z, S[2 * (SL)].w);                        \
    w_[2] = cvt_pk_bf16(S[2 * (SL) + 1].x, S[2 * (SL) + 1].y);                \
    w_[3] = cvt_pk_bf16(S[2 * (SL) + 1].z, S[2 * (SL) + 1].w);                \
    *(u32x4*)((DSTB) + ((SL) << 13) + bwr) = w_;                              \
  } while (0)

#define READS_A(D, MH)                                                        \
  do {                                                                        \
    const char* pA_ = sA + (D) * 32768 + ((MH) << 13) + aB;                   \
    af[0][0] = *(const u32x4*)(pA_ + cs0);                                    \
    af[0][1] = *(const u32x4*)(pA_ + cs1);                                    \
    af[1][0] = *(const u32x4*)(pA_ + 2048 + cs0);                             \
    af[1][1] = *(const u32x4*)(pA_ + 2048 + cs1);                             \
    af[2][0] = *(const u32x4*)(pA_ + 4096 + cs0);                             \
    af[2][1] = *(const u32x4*)(pA_ + 4096 + cs1);                             \
    af[3][0] = *(const u32x4*)(pA_ + 6144 + cs0);                             \
    af[3][1] = *(const u32x4*)(pA_ + 6144 + cs1);                             \
  } while (0)
#define READS_B(D, NH)                                                        \
  do {                                                                        \
    const char* pB_ = sB + (D) * 32768 + ((NH) << 12) + bB;                   \
    bf[0][0] = *(const u32x4*)(pB_ + cs0);                                    \
    bf[0][1] = *(const u32x4*)(pB_ + cs1);                                    \
    bf[1][0] = *(const u32x4*)(pB_ + 2048 + cs0);                             \
    bf[1][1] = *(const u32x4*)(pB_ + 2048 + cs1);                             \
  } while (0)

#define MFMA_Q(MH, NH)                                                        \
  do {                                                                        \
    __builtin_amdgcn_s_setprio(1);                                            \
    _Pragma("unroll")                                                         \
    for (int m = 0; m < 4; ++m)                                               \
      _Pragma("unroll")                                                       \
      for (int n = 0; n < 2; ++n) {                                           \
        MFMA_BF16_16x16x32(acc[(MH) * 4 + m][(NH) * 2 + n], af[m][0],         \
                           bf[n][0]);                                         \
        MFMA_BF16_16x16x32(acc[(MH) * 4 + m][(NH) * 2 + n], af[m][1],         \
                           bf[n][1]);                                         \
      }                                                                       \
    __builtin_amdgcn_s_setprio(0);                                            \
  } while (0)

// Full K-tile iteration in snake order. Phase p packs slice p and reloads it.
#define ITER_Z(D, KT, DOPACK, DOSTAGE, DOLOAD, HV0, HV1, HV2, HV3, TV)        \
  do {                                                                        \
    /* phase 0: (0,0) reads A0+B0; stage A(kt+1); load B(kt+2) s0 */          \
    HV0;                                                                      \
    SFENCE();                                                                 \
    if (DOPACK) { PACK_S(sB + ((D) ^ 1) * 32768, 0); }                        \
    SFENCE();                                                                 \
    READS_A(D, 0);                                                            \
    READS_B(D, 0);                                                            \
    SFENCE();                                                                 \
    if (DOSTAGE) { STAGE_A4((D) ^ 1, (KT) + 1); }                             \
    SFENCE();                                                                 \
    if (DOLOAD) { LOADB_S((KT) + 2, 0); }                                     \
    SFENCE();                                                                 \
    BARRIER();                                                                \
    WAIT_LGKM0();                                                             \
    SFENCE();                                                                 \
    MFMA_Q(0, 0);                                                             \
    BARRIER();                                                                \
    /* phase 1: (1,0) reads A1 (B0 reused) */                                 \
    HV1;                                                                      \
    SFENCE();                                                                 \
    if (DOPACK) { PACK_S(sB + ((D) ^ 1) * 32768, 1); }                        \
    SFENCE();                                                                 \
    READS_A(D, 1);                                                            \
    SFENCE();                                                                 \
    if (DOLOAD) { LOADB_S((KT) + 2, 1); }                                     \
    SFENCE();                                                                 \
    BARRIER();                                                                \
    WAIT_LGKM0();                                                             \
    SFENCE();                                                                 \
    MFMA_Q(1, 0);                                                             \
    BARRIER();                                                                \
    /* phase 2: (1,1) reads B1 (A1 reused) */                                 \
    HV2;                                                                      \
    SFENCE();                                                                 \
    if (DOPACK) { PACK_S(sB + ((D) ^ 1) * 32768, 2); }                        \
    SFENCE();                                                                 \
    READS_B(D, 1);                                                            \
    SFENCE();                                                                 \
    if (DOLOAD) { LOADB_S((KT) + 2, 2); }                                     \
    SFENCE();                                                                 \
    BARRIER();                                                                \
    WAIT_LGKM0();                                                             \
    SFENCE();                                                                 \
    MFMA_Q(1, 1);                                                             \
    BARRIER();                                                                \
    /* phase 3: (0,1) reads A0 again (B1 reused) */                           \
    HV3;                                                                      \
    SFENCE();                                                                 \
    if (DOPACK) { PACK_S(sB + ((D) ^ 1) * 32768, 3); }                        \
    SFENCE();                                                                 \
    READS_A(D, 0);                                                            \
    SFENCE();                                                                 \
    if (DOLOAD) { LOADB_S((KT) + 2, 3); }                                     \
    SFENCE();                                                                 \
    BARRIER();                                                                \
    WAIT_LGKM0();                                                             \
    SFENCE();                                                                 \
    MFMA_Q(0, 1);                                                             \
    TV;                                                                       \
    BARRIER();                                                                \
  } while (0)

  u32x4 af[4][2], bf[2][2];
  float4 S[8];

  // ---- prologue: A(0)->bufA0; B(0)->S->pack->bufB0; B(1)->S in flight ----
  STAGE_A4(0, 0);
  SFENCE();
  LOADB_S(0, 0); LOADB_S(0, 1); LOADB_S(0, 2); LOADB_S(0, 3);
  SFENCE();
  WAIT_VM0();
  SFENCE();
  PACK_S(sB, 0); PACK_S(sB, 1); PACK_S(sB, 2); PACK_S(sB, 3);
  SFENCE();
  LOADB_S(1, 0); LOADB_S(1, 1); LOADB_S(1, 2); LOADB_S(1, 3);
  SFENCE();
  WAIT_LGKM0();
  BARRIER();
  // steady invariant entering iter kt: B(kt+1) x8 outstanding.

#pragma unroll 1
  for (int kt = 0; kt < 62; ++kt) {
    const int d = kt & 1;
    ITER_Z(d, kt, 1, 1, 1, WAIT_VM6(), WAIT_VM10(), WAIT_VM10(), WAIT_VM10(),
           WAIT_VM8());
  }
  // kt = 62: pack B(63), stage A(63), no loads (waits re-audited for r13)
  ITER_Z(0, 62, 1, 1, 0, WAIT_VM6(), WAIT_VM8(), WAIT_VM6(), WAIT_VM4(),
         WAIT_VM0());
  // kt = 63: compute only
  ITER_Z(1, 63, 0, 0, 0, NOWAIT(), NOWAIT(), NOWAIT(), NOWAIT(), NOWAIT());

  // C/D layout: col = lane&15, row = (lane>>4)*4 + j
#pragma unroll
  for (int m = 0; m < 8; ++m) {
    const int r0 = aRow0 + wr * 128 + m * 16 + lk * 4;
#pragma unroll
    for (int n = 0; n < 4; ++n) {
      const int col = bCol0 + wc * 64 + n * 16 + lr;
#pragma unroll
      for (int j = 0; j < 4; ++j)
        Ct[(size_t)(r0 + j) * 4096 + col] = f2bf_rne(acc[m][n][j]);
    }
  }
#undef STAGE_A4
#undef LOADB_S
#undef PACK_S
#undef READS_A
#undef READS_B
#undef MFMA_Q
#undef ITER_Z
}

// ---------------------------------------------------------------------------
// gemm_out SPLIT-K=2: partial[s][n, t*512+r] = sum_{d in half s} z*dec.
// 512 blocks, 128x64 tile, 64 K-steps. Quad-buffered depth-3 counted-vmcnt
// pipeline (verified r10/r13). Slot-XOR swizzle.
// ---------------------------------------------------------------------------
__global__ __launch_bounds__(256, 2) void gemm_out_kernel(
    const u16* __restrict__ Z,    // [8][512][4096]
    const u16* __restrict__ Dec,  // [8][512][4096]
    float* __restrict__ part) {   // [2][512][4096]
  __shared__ char sm[49152];      // 4 bufs x (A 8KB + B 4KB)
  const int lb = blockIdx.x;
  const int sp = lb >> 8;                       // K split 0/1
  const int ls = lb & 255;
  const int swz = ((ls & 7) << 5) | (ls >> 3);  // 256 % 8 == 0
  const int t = swz >> 5;
  const int rem = swz & 31;
  const int nb = rem >> 2, mb = rem & 3;
  const u16* At = Z + ((size_t)t << 21);
  const u16* Bt = Dec + ((size_t)t << 21);
  float* po = part + (size_t)sp * (512 * 4096);
  const int aRow0 = mb << 7, bCol0 = nb << 6;
  const int KS = sp << 11;                      // element offset of K half
  const int tid = threadIdx.x;
  const int wv = tid >> 6, ln = tid & 63;
  const int lr = ln & 15, lk = ln >> 4;
  const int wr = wv >> 1, wc = wv & 1;

  fx4 acc[4][2] = {};

  const int kswz = (((tid & 3) ^ ((tid >> 3) & 3)) << 3);
  const u16* Asrc = At + (size_t)(aRow0 + (tid >> 2)) * 4096 + KS + kswz;
  const u16* Bsrc = Bt + (size_t)(bCol0 + (tid >> 2)) * 4096 + KS + kswz;
  const int gr = (lr >> 1) & 3;
  const int aof = (wr * 64 + lr) * 64 + ((lk ^ gr) << 4);          // + m*1024
  const int bof = 8192 + (wc * 32 + lr) * 64 + ((lk ^ gr) << 4);   // + n*1024

#define STAGE_O(buf, kofs)                                                   \
  do {                                                                       \
    _Pragma("unroll")                                                        \
    for (int c = 0; c < 2; ++c)                                              \
      __builtin_amdgcn_global_load_lds(                                      \
          (gvoid*)(Asrc + (size_t)(c << 6) * 4096 + (kofs)),                 \
          (lvoid*)((buf) + c * 4096 + tid * 16), 16, 0, 0);                  \
    __builtin_amdgcn_global_load_lds((gvoid*)(Bsrc + (kofs)),                \
                                     (lvoid*)((buf) + 8192 + tid * 16), 16,  \
                                     0, 0);                                  \
  } while (0)

  char* b0 = sm;
  char* b1 = sm + 12288;
  char* b2 = sm + 24576;
  char* b3 = sm + 36864;
  STAGE_O(b0, 0);
  STAGE_O(b1, 32);
  STAGE_O(b2, 64);
  WAIT_VM6();                     // stage(0) complete; 1,2 in flight
  BARRIER();

#pragma unroll 1
  for (int kt = 0; kt < 64; ++kt) {
    if (kt + 3 < 64) STAGE_O(b3, (kt + 3) << 5);
    u32x4 af[4], bf[2];
#pragma unroll
    for (int m = 0; m < 4; ++m)
      af[m] = *(const u32x4*)(b0 + aof + m * 1024);
#pragma unroll
    for (int n = 0; n < 2; ++n)
      bf[n] = *(const u32x4*)(b0 + bof + n * 1024);
    WAIT_LGKM0();
    SFENCE();
#pragma unroll
    for (int m = 0; m < 4; ++m)
#pragma unroll
      for (int n = 0; n < 2; ++n)
        MFMA_BF16_16x16x32(acc[m][n], af[m], bf[n]);
    if (kt + 3 < 64) {
      WAIT_VM6();                 // stage(kt+1) done; kt+2, kt+3 in flight
    } else if (kt + 2 < 64) {
      WAIT_VM3();
    } else {
      WAIT_VM0();
    }
    BARRIER();
    char* tmp = b0; b0 = b1; b1 = b2; b2 = b3; b3 = tmp;
  }

#pragma unroll
  for (int n = 0; n < 2; ++n) {
    const int colg = (t << 9) + bCol0 + wc * 32 + n * 16 + lr;
#pragma unroll
    for (int m = 0; m < 4; ++m) {
      const int r0 = aRow0 + wr * 64 + m * 16 + lk * 4;
#pragma unroll
      for (int j = 0; j < 4; ++j)
        po[(size_t)(r0 + j) * 4096 + colg] = acc[m][n][j];
    }
  }
#undef STAGE_O
}

// ---------------------------------------------------------------------------
// combine: out = part0 + part1 + bias. 2048 blocks x 256 x float4.
// ---------------------------------------------------------------------------
__global__ __launch_bounds__(256) void combine_kernel(
    const float* __restrict__ p0, const float* __restrict__ p1,
    const float* __restrict__ bias, float* __restrict__ out) {
  const int i = blockIdx.x * 256 + threadIdx.x;
  float4 a = ((const float4*)p0)[i];
  float4 b = ((const float4*)p1)[i];
  float4 bv = ((const float4*)bias)[i & 1023];
  float4 o;
  o.x = a.x + b.x + bv.x;
  o.y = a.y + b.y + bv.y;
  o.z = a.z + b.z + bv.z;
  o.w = a.w + b.w + bv.w;
  ((float4*)out)[i] = o;
}

// ---------------------------------------------------------------------------
extern "C" void kernel_launch(void* const* d_in, const int* in_sizes, int n_in,
                              void* d_out, int out_size, void* d_ws, size_t ws_size,
                              hipStream_t stream) {
  const float* x       = (const float*)d_in[0];   // [512][4096]
  const float* cw      = (const float*)d_in[1];   // [16384][4096]
  const int*   indices = (const int*)d_in[2];     // [8][512][4]
  const float* rot     = (const float*)d_in[3];   // [8][4096][4096]
  const float* scales  = (const float*)d_in[4];   // [8]
  const float* bias    = (const float*)d_in[5];   // [4096]
  float* out = (float*)d_out;
  char* ws = (char*)d_ws;

  u16*   xb   = (u16*)(ws);                         // 4 MiB
  u16*   dec  = (u16*)(ws + ((size_t)4 << 20));     // 32 MiB
  u16*   z    = (u16*)(ws + ((size_t)36 << 20));    // 32 MiB
  float* part = (float*)(ws + ((size_t)68 << 20));  // 16 MiB (2 x 8 MiB)

  decode_kernel<<<dim3(4096), dim3(256), 0, stream>>>(cw, indices, scales, dec);
  cvtx_kernel<<<dim3(2048), dim3(256), 0, stream>>>(x, xb);
  gemm_z_kernel<<<dim3(256), dim3(512), 0, stream>>>(xb, rot, z);
  gemm_out_kernel<<<dim3(512), dim3(256), 0, stream>>>(z, dec, part);
  combine_kernel<<<dim3(2048), dim3(256), 0, stream>>>(
      part, part + (size_t)512 * 4096, bias, out);
}

// Round 15
// 278.215 us; speedup vs baseline: 2.2022x; 1.0041x over previous
//
#include <hip/hip_runtime.h>

typedef unsigned int uint32;
typedef unsigned short u16;
typedef float fx4 __attribute__((ext_vector_type(4)));
typedef uint32 u32x4 __attribute__((ext_vector_type(4)));

typedef const __attribute__((address_space(1))) void gvoid;
typedef __attribute__((address_space(3))) void lvoid;

#define MFMA_BF16_16x16x32(acc, a, b) \
  asm("v_mfma_f32_16x16x32_bf16 %0, %1, %2, %0" : "+v"(acc) : "v"(a), "v"(b))

#define WAIT_LGKM0() asm volatile("s_waitcnt lgkmcnt(0)" ::: "memory")
#define WAIT_VM0()   asm volatile("s_waitcnt vmcnt(0)" ::: "memory")
#define WAIT_VM3()   asm volatile("s_waitcnt vmcnt(3)" ::: "memory")
#define WAIT_VM4()   asm volatile("s_waitcnt vmcnt(4)" ::: "memory")
#define WAIT_VM6()   asm volatile("s_waitcnt vmcnt(6)" ::: "memory")
#define WAIT_VM8()   asm volatile("s_waitcnt vmcnt(8)" ::: "memory")
#define WAIT_VM10()  asm volatile("s_waitcnt vmcnt(10)" ::: "memory")
#define SFENCE()     __builtin_amdgcn_sched_barrier(0)
#define BARRIER()    do { __builtin_amdgcn_s_barrier(); asm volatile("" ::: "memory"); } while (0)
#define NOWAIT()     do { } while (0)

__device__ __forceinline__ u16 f2bf_rne(float f) {
  uint32 u = __builtin_bit_cast(uint32, f);
  u += 0x7FFFu + ((u >> 16) & 1u);
  return (u16)(u >> 16);
}

__device__ __forceinline__ uint32 cvt_pk_bf16(float lo, float hi) {
  uint32 r;
  asm("v_cvt_pk_bf16_f32 %0, %1, %2" : "=v"(r) : "v"(lo), "v"(hi));
  return r;
}

// ---------------------------------------------------------------------------
// x (fp32) -> bf16
// ---------------------------------------------------------------------------
__global__ __launch_bounds__(256) void cvtx_kernel(const float* __restrict__ x,
                                                   u16* __restrict__ xb) {
  const int i = blockIdx.x * 256 + threadIdx.x;
  float4 v = ((const float4*)x)[i];
  ushort4 o;
  o.x = f2bf_rne(v.x);
  o.y = f2bf_rne(v.y);
  o.z = f2bf_rne(v.z);
  o.w = f2bf_rne(v.w);
  ((ushort4*)xb)[i] = o;
}

// ---------------------------------------------------------------------------
// decode body (512 threads, r12-verified): 16 rows per block
// ---------------------------------------------------------------------------
__device__ __forceinline__ void decode_body(
    int bid, const float* __restrict__ cw, const int* __restrict__ indices,
    const float* __restrict__ scales, u16* __restrict__ dec) {
  const int tid = threadIdx.x;
#pragma unroll 1
  for (int rr = 0; rr < 16; ++rr) {
    const int row = bid * 16 + rr;       // t*512 + r
    const int t = row >> 9;
    const int* ip = indices + (size_t)row * 4;
    const float* c0 = cw + (size_t)ip[0] * 4096;
    const float* c1 = cw + (size_t)ip[1] * 4096;
    const float* c2 = cw + (size_t)ip[2] * 4096;
    const float* c3 = cw + (size_t)ip[3] * 4096;
    const float s = scales[t] * 0.25f;
    u16* orow = dec + (size_t)row * 4096;
#pragma unroll
    for (int j = 0; j < 2; ++j) {
      const int d = j * 2048 + tid * 4;
      float4 a = *(const float4*)(c0 + d);
      float4 b = *(const float4*)(c1 + d);
      float4 c = *(const float4*)(c2 + d);
      float4 e = *(const float4*)(c3 + d);
      ushort4 o;
      o.x = f2bf_rne((a.x + b.x + c.x + e.x) * s);
      o.y = f2bf_rne((a.y + b.y + c.y + e.y) * s);
      o.z = f2bf_rne((a.z + b.z + c.z + e.z) * s);
      o.w = f2bf_rne((a.w + b.w + c.w + e.w) * s);
      *(ushort4*)(orow + d) = o;
    }
  }
}

// ---------------------------------------------------------------------------
// Fused: blocks [0,256) decode (overlaps HBM under GEMM); blocks [256,512)
// gemm_z: z[t] = x_bf16 @ rot[t]^T.  256x256 tile, BK=64, 8 waves (2x4),
// wave tile 128x64, acc[8][4]. 1 block/CU, LDS 128 KB. 4 quadrant-phases per
// K-tile in SNAKE order (r14-verified): reads 32 b128/K-tile. Slot-XOR LDS,
// pre-swizzled-source A DMA, coalesced reg-staged B slice-per-phase with
// counted vmcnt (FIFO-audited, identical to r13/r14).
// ---------------------------------------------------------------------------
__global__ __launch_bounds__(512, 2) void fused_z_decode_kernel(
    const u16* __restrict__ Xb,    // [512][4096] bf16
    const float* __restrict__ rot, // [8][4096][4096] fp32
    u16* __restrict__ Z,           // [8][512][4096] bf16
    const float* __restrict__ cw, const int* __restrict__ indices,
    const float* __restrict__ scales, u16* __restrict__ dec) {
  __shared__ char sA[65536];       // 2 bufs x [256 rows][128B] (slot-XOR)
  __shared__ char sB[65536];

  const int bid = blockIdx.x;
  if (bid < 256) {
    decode_body(bid, cw, indices, scales, dec);
    return;
  }
  const int lb = bid - 256;
  const int swz = ((lb & 7) << 5) | (lb >> 3);   // XCD-chunked, 256%8==0
  const int t = swz >> 5;
  const int rem = swz & 31;
  const int nb = rem >> 1, mb = rem & 1;         // mb-sharers adjacent
  const float* Bt = rot + ((size_t)t << 24);
  u16* Ct = Z + ((size_t)t << 21);
  const int aRow0 = mb << 8, bCol0 = nb << 8;
  const int tid = threadIdx.x;
  const int wv = tid >> 6, ln = tid & 63;
  const int lr = ln & 15, lk = ln >> 4;
  const int wr = wv >> 2, wc = wv & 3;

  fx4 acc[8][4] = {};

  const u16* Asrc = Xb + (size_t)(aRow0 + (tid >> 3)) * 4096 +
                    (((tid & 7) ^ ((tid >> 3) & 7)) << 3);
  const float* Bsrc = Bt + (size_t)(bCol0 + (tid >> 3)) * 4096 + ((tid & 7) << 3);
  const int bwr = (tid >> 3) * 128 + (((tid & 7) ^ ((tid >> 3) & 7)) << 4);
  const int cs0 = (lk ^ (lr & 7)) << 4;
  const int cs1 = ((4 + lk) ^ (lr & 7)) << 4;
  const int aB = (wr * 128 + lr) * 128;  // + MH*8192 + m*2048 + cs
  const int bB = (wc * 64 + lr) * 128;   // + NH*4096 + n*2048 + cs

#define STAGE_A4(DB, KT)                                                      \
  _Pragma("unroll")                                                           \
  for (int c = 0; c < 4; ++c)                                                 \
    __builtin_amdgcn_global_load_lds(                                         \
        (gvoid*)(Asrc + (size_t)(c << 6) * 4096 + ((KT) << 6)),               \
        (lvoid*)(sA + (DB) * 32768 + (c << 13) + (wv << 10) + ln * 16),       \
        16, 0, 0)

#define LOADB_S(KT, SL)                                                       \
  do {                                                                        \
    const float* bp_ = Bsrc + (size_t)((SL) << 6) * 4096 + ((KT) << 6);       \
    S[2 * (SL)] = *(const float4*)(bp_);                                      \
    S[2 * (SL) + 1] = *(const float4*)(bp_ + 4);                              \
  } while (0)

#define PACK_S(DSTB, SL)                                                      \
  do {                                                                        \
    u32x4 w_;                                                                 \
    w_[0] = cvt_pk_bf16(S[2 * (SL)].x, S[2 * (SL)].y);                        \
    w_[1] = cvt_pk_bf16(S[2 * (SL)].z, S[2 * (SL)].w);                        \
    w_[2] = cvt_pk_bf16(S[2 * (SL) + 1].x, S[2 * (SL) + 1].y);                \
    w_[3] = cvt_pk_bf16(S[2 * (SL) + 1].z, S[2 * (SL) + 1].w);                \
    *(u32x4*)((DSTB) + ((SL) << 13) + bwr) = w_;                              \
  } while (0)

#define READS_A(D, MH)                                                        \
  do {                                                                        \
    const char* pA_ = sA + (D) * 32768 + ((MH) << 13) + aB;                   \
    af[0][0] = *(const u32x4*)(pA_ + cs0);                                    \
    af[0][1] = *(const u32x4*)(pA_ + cs1);                                    \
    af[1][0] = *(const u32x4*)(pA_ + 2048 + cs0);                             \
    af[1][1] = *(const u32x4*)(pA_ + 2048 + cs1);                             \
    af[2][0] = *(const u32x4*)(pA_ + 4096 + cs0);                             \
    af[2][1] = *(const u32x4*)(pA_ + 4096 + cs1);                             \
    af[3][0] = *(const u32x4*)(pA_ + 6144 + cs0);                             \
    af[3][1] = *(const u32x4*)(pA_ + 6144 + cs1);                             \
  } while (0)
#define READS_B(D, NH)                                                        \
  do {                                                                        \
    const char* pB_ = sB + (D) * 32768 + ((NH) << 12) + bB;                   \
    bf[0][0] = *(const u32x4*)(pB_ + cs0);                                    \
    bf[0][1] = *(const u32x4*)(pB_ + cs1);                                    \
    bf[1][0] = *(const u32x4*)(pB_ + 2048 + cs0);                             \
    bf[1][1] = *(const u32x4*)(pB_ + 2048 + cs1);                             \
  } while (0)

#define MFMA_Q(MH, NH)                                                        \
  do {                                                                        \
    __builtin_amdgcn_s_setprio(1);                                            \
    _Pragma("unroll")                                                         \
    for (int m = 0; m < 4; ++m)                                               \
      _Pragma("unroll")                                                       \
      for (int n = 0; n < 2; ++n) {                                           \
        MFMA_BF16_16x16x32(acc[(MH) * 4 + m][(NH) * 2 + n], af[m][0],         \
                           bf[n][0]);                                         \
        MFMA_BF16_16x16x32(acc[(MH) * 4 + m][(NH) * 2 + n], af[m][1],         \
                           bf[n][1]);                                         \
      }                                                                       \
    __builtin_amdgcn_s_setprio(0);                                            \
  } while (0)

#define ITER_Z(D, KT, DOPACK, DOSTAGE, DOLOAD, HV0, HV1, HV2, HV3, TV)        \
  do {                                                                        \
    HV0;                                                                      \
    SFENCE();                                                                 \
    if (DOPACK) { PACK_S(sB + ((D) ^ 1) * 32768, 0); }                        \
    SFENCE();                                                                 \
    READS_A(D, 0);                                                            \
    READS_B(D, 0);                                                            \
    SFENCE();                                                                 \
    if (DOSTAGE) { STAGE_A4((D) ^ 1, (KT) + 1); }                             \
    SFENCE();                                                                 \
    if (DOLOAD) { LOADB_S((KT) + 2, 0); }                                     \
    SFENCE();                                                                 \
    BARRIER();                                                                \
    WAIT_LGKM0();                                                             \
    SFENCE();                                                                 \
    MFMA_Q(0, 0);                                                             \
    BARRIER();                                                                \
    HV1;                                                                      \
    SFENCE();                                                                 \
    if (DOPACK) { PACK_S(sB + ((D) ^ 1) * 32768, 1); }                        \
    SFENCE();                                                                 \
    READS_A(D, 1);                                                            \
    SFENCE();                                                                 \
    if (DOLOAD) { LOADB_S((KT) + 2, 1); }                                     \
    SFENCE();                                                                 \
    BARRIER();                                                                \
    WAIT_LGKM0();                                                             \
    SFENCE();                                                                 \
    MFMA_Q(1, 0);                                                             \
    BARRIER();                                                                \
    HV2;                                                                      \
    SFENCE();                                                                 \
    if (DOPACK) { PACK_S(sB + ((D) ^ 1) * 32768, 2); }                        \
    SFENCE();                                                                 \
    READS_B(D, 1);                                                            \
    SFENCE();                                                                 \
    if (DOLOAD) { LOADB_S((KT) + 2, 2); }                                     \
    SFENCE();                                                                 \
    BARRIER();                                                                \
    WAIT_LGKM0();                                                             \
    SFENCE();                                                                 \
    MFMA_Q(1, 1);                                                             \
    BARRIER();                                                                \
    HV3;                                                                      \
    SFENCE();                                                                 \
    if (DOPACK) { PACK_S(sB + ((D) ^ 1) * 32768, 3); }                        \
    SFENCE();                                                                 \
    READS_A(D, 0);                                                            \
    SFENCE();                                                                 \
    if (DOLOAD) { LOADB_S((KT) + 2, 3); }                                     \
    SFENCE();                                                                 \
    BARRIER();                                                                \
    WAIT_LGKM0();                                                             \
    SFENCE();                                                                 \
    MFMA_Q(0, 1);                                                             \
    TV;                                                                       \
    BARRIER();                                                                \
  } while (0)

  u32x4 af[4][2], bf[2][2];
  float4 S[8];

  // ---- prologue: A(0)->bufA0; B(0)->S->pack->bufB0; B(1)->S in flight ----
  STAGE_A4(0, 0);
  SFENCE();
  LOADB_S(0, 0); LOADB_S(0, 1); LOADB_S(0, 2); LOADB_S(0, 3);
  SFENCE();
  WAIT_VM0();
  SFENCE();
  PACK_S(sB, 0); PACK_S(sB, 1); PACK_S(sB, 2); PACK_S(sB, 3);
  SFENCE();
  LOADB_S(1, 0); LOADB_S(1, 1); LOADB_S(1, 2); LOADB_S(1, 3);
  SFENCE();
  WAIT_LGKM0();
  BARRIER();
  // steady invariant entering iter kt: B(kt+1) x8 outstanding.

#pragma unroll 1
  for (int kt = 0; kt < 62; ++kt) {
    const int d = kt & 1;
    ITER_Z(d, kt, 1, 1, 1, WAIT_VM6(), WAIT_VM10(), WAIT_VM10(), WAIT_VM10(),
           WAIT_VM8());
  }
  // kt = 62: pack B(63), stage A(63), no loads
  ITER_Z(0, 62, 1, 1, 0, WAIT_VM6(), WAIT_VM8(), WAIT_VM6(), WAIT_VM4(),
         WAIT_VM0());
  // kt = 63: compute only
  ITER_Z(1, 63, 0, 0, 0, NOWAIT(), NOWAIT(), NOWAIT(), NOWAIT(), NOWAIT());

  // C/D layout: col = lane&15, row = (lane>>4)*4 + j
#pragma unroll
  for (int m = 0; m < 8; ++m) {
    const int r0 = aRow0 + wr * 128 + m * 16 + lk * 4;
#pragma unroll
    for (int n = 0; n < 4; ++n) {
      const int col = bCol0 + wc * 64 + n * 16 + lr;
#pragma unroll
      for (int j = 0; j < 4; ++j)
        Ct[(size_t)(r0 + j) * 4096 + col] = f2bf_rne(acc[m][n][j]);
    }
  }
#undef STAGE_A4
#undef LOADB_S
#undef PACK_S
#undef READS_A
#undef READS_B
#undef MFMA_Q
#undef ITER_Z
}

// ---------------------------------------------------------------------------
// gemm_out (r10-verified): out[n, t*512+r] = sum_d z*dec + bias. 128x64
// tile, BK=32, full K (128 steps). Quad-buffered depth-3 counted-vmcnt
// pipeline; slot-XOR swizzle. 256 blocks (1/CU).
// ---------------------------------------------------------------------------
__global__ __launch_bounds__(256, 2) void gemm_out_kernel(
    const u16* __restrict__ Z,    // [8][512][4096]
    const u16* __restrict__ Dec,  // [8][512][4096]
    const float* __restrict__ bias,
    float* __restrict__ out) {    // [512][4096]
  __shared__ char sm[49152];      // 4 bufs x (A 8KB + B 4KB)
  const int lb = blockIdx.x;
  const int swz = ((lb & 7) << 5) | (lb >> 3);  // 256 % 8 == 0
  const int t = swz >> 5;
  const int rem = swz & 31;
  const int nb = rem >> 2, mb = rem & 3;
  const u16* At = Z + ((size_t)t << 21);
  const u16* Bt = Dec + ((size_t)t << 21);
  const int aRow0 = mb << 7, bCol0 = nb << 6;
  const int tid = threadIdx.x;
  const int wv = tid >> 6, ln = tid & 63;
  const int lr = ln & 15, lk = ln >> 4;
  const int wr = wv >> 1, wc = wv & 1;

  fx4 acc[4][2] = {};

  const int kswz = (((tid & 3) ^ ((tid >> 3) & 3)) << 3);
  const u16* Asrc = At + (size_t)(aRow0 + (tid >> 2)) * 4096 + kswz;
  const u16* Bsrc = Bt + (size_t)(bCol0 + (tid >> 2)) * 4096 + kswz;
  const int gr = (lr >> 1) & 3;
  const int aof = (wr * 64 + lr) * 64 + ((lk ^ gr) << 4);          // + m*1024
  const int bof = 8192 + (wc * 32 + lr) * 64 + ((lk ^ gr) << 4);   // + n*1024

#define STAGE_O(buf, kofs)                                                   \
  do {                                                                       \
    _Pragma("unroll")                                                        \
    for (int c = 0; c < 2; ++c)                                              \
      __builtin_amdgcn_global_load_lds(                                      \
          (gvoid*)(Asrc + (size_t)(c << 6) * 4096 + (kofs)),                 \
          (lvoid*)((buf) + c * 4096 + tid * 16), 16, 0, 0);                  \
    __builtin_amdgcn_global_load_lds((gvoid*)(Bsrc + (kofs)),                \
                                     (lvoid*)((buf) + 8192 + tid * 16), 16,  \
                                     0, 0);                                  \
  } while (0)

  char* b0 = sm;
  char* b1 = sm + 12288;
  char* b2 = sm + 24576;
  char* b3 = sm + 36864;
  STAGE_O(b0, 0);
  STAGE_O(b1, 32);
  STAGE_O(b2, 64);
  WAIT_VM6();                     // stage(0) complete; 1,2 in flight
  BARRIER();

#pragma unroll 1
  for (int kt = 0; kt < 128; ++kt) {
    if (kt + 3 < 128) STAGE_O(b3, (kt + 3) << 5);
    u32x4 af[4], bf[2];
#pragma unroll
    for (int m = 0; m < 4; ++m)
      af[m] = *(const u32x4*)(b0 + aof + m * 1024);
#pragma unroll
    for (int n = 0; n < 2; ++n)
      bf[n] = *(const u32x4*)(b0 + bof + n * 1024);
    WAIT_LGKM0();
    SFENCE();
#pragma unroll
    for (int m = 0; m < 4; ++m)
#pragma unroll
      for (int n = 0; n < 2; ++n)
        MFMA_BF16_16x16x32(acc[m][n], af[m], bf[n]);
    if (kt + 3 < 128) {
      WAIT_VM6();                 // stage(kt+1) done; kt+2, kt+3 in flight
    } else if (kt + 2 < 128) {
      WAIT_VM3();                 // kt = 125
    } else {
      WAIT_VM0();                 // kt = 126, 127
    }
    BARRIER();
    char* tmp = b0; b0 = b1; b1 = b2; b2 = b3; b3 = tmp;
  }

#pragma unroll
  for (int n = 0; n < 2; ++n) {
    const int colg = (t << 9) + bCol0 + wc * 32 + n * 16 + lr;
    const float bv = bias[colg];
#pragma unroll
    for (int m = 0; m < 4; ++m) {
      const int r0 = aRow0 + wr * 64 + m * 16 + lk * 4;
#pragma unroll
      for (int j = 0; j < 4; ++j)
        out[(size_t)(r0 + j) * 4096 + colg] = acc[m][n][j] + bv;
    }
  }
#undef STAGE_O
}

// ---------------------------------------------------------------------------
extern "C" void kernel_launch(void* const* d_in, const int* in_sizes, int n_in,
                              void* d_out, int out_size, void* d_ws, size_t ws_size,
                              hipStream_t stream) {
  const float* x       = (const float*)d_in[0];   // [512][4096]
  const float* cw      = (const float*)d_in[1];   // [16384][4096]
  const int*   indices = (const int*)d_in[2];     // [8][512][4]
  const float* rot     = (const float*)d_in[3];   // [8][4096][4096]
  const float* scales  = (const float*)d_in[4];   // [8]
  const float* bias    = (const float*)d_in[5];   // [4096]
  float* out = (float*)d_out;
  char* ws = (char*)d_ws;

  u16* xb  = (u16*)(ws);                          // 4 MiB
  u16* dec = (u16*)(ws + ((size_t)4 << 20));      // 32 MiB
  u16* z   = (u16*)(ws + ((size_t)36 << 20));     // 32 MiB

  cvtx_kernel<<<dim3(2048), dim3(256), 0, stream>>>(x, xb);
  fused_z_decode_kernel<<<dim3(512), dim3(512), 0, stream>>>(
      xb, rot, z, cw, indices, scales, dec);
  gemm_out_kernel<<<dim3(256), dim3(256), 0, stream>>>(z, dec, bias, out);
}